// Round 3
// baseline (841.418 us; speedup 1.0000x reference)
//
#include <hip/hip_runtime.h>
#include <hip/hip_cooperative_groups.h>
#include <math.h>

namespace cg = cooperative_groups;

#define NUM_USERS 100000
#define NUM_ITEMS 200000
#define N_NODES   300000   // NUM_USERS + NUM_ITEMS
#define EMB       64
#define NUM_INTER 1000000
#define MAX_SLOTS (2 * NUM_INTER + 3 * N_NODES + 16)   // rows padded to x4
#define BATCH     16384

// ---- bucketed CSR builder geometry ----
#define BSHIFT 9
#define BNODES 512
#define NBKT   ((N_NODES + BNODES - 1) / BNODES)    // 586
#define CAP    6144                                 // refs per bucket (max expected ~5400)
#define NSCAT  490                                  // scatter blocks (287K cursor atomics)
#define CONV_UNITS ((N_NODES * 8) / 256)            // 9375 (exact)

typedef int      vint4 __attribute__((ext_vector_type(4)));
typedef _Float16 half8 __attribute__((ext_vector_type(8)));

struct Params {
    const float* ue; const float* ie; const float* lw;
    const int* iu; const int* ii; const int* uid; const int* iid;
    float* out;
    int* cursor; uint2* pairs;
    int* deg; float* dinv; float* d2; float* rcp;
    int* lofs; int* row_start; int* bkt_pad; int* bkt_base;
    int* flag; unsigned char* qflag; int* work;
    int* nbr;
    _Float16* semb; _Float16* z1; _Float16* z2;
    float* w4;
};

__global__ __launch_bounds__(256) void mega_k(Params P) {
    cg::grid_group grid = cg::this_grid();
    const int tid  = threadIdx.x;
    const int bid  = blockIdx.x;
    const int nblk = gridDim.x;
    const int gt   = nblk * 256;
    const int g    = bid * 256 + tid;

    __shared__ int smem[1184];
    __shared__ int wsh;

    // ================= P0: zero flag, qflag, cursor, work counter =================
    for (int i = g; i < N_NODES; i += gt) P.flag[i] = 0;
    unsigned* q4 = (unsigned*)P.qflag;
    for (int i = g; i < (N_NODES + 3) / 4; i += gt) q4[i] = 0u;
    for (int i = g; i < NBKT * 16; i += gt) P.cursor[i] = 0;
    if (g == 0) P.work[0] = 0;
    grid.sync();

    // ================= P1: qflag/flag of queried (blocks<16) + bucket scatter =====
    {
        int qb = nblk < 16 ? nblk : 16;
        if (bid < qb) {
            for (int k = bid * 256 + tid; k < BATCH * 2; k += qb * 256) {
                int node = (k & 1) ? (NUM_USERS + P.iid[k >> 1]) : P.uid[k >> 1];
                P.qflag[node] = 1;
                P.flag[node]  = 1;
            }
        }
        int nscat = nblk < NSCAT ? nblk : NSCAT;
        if (bid < nscat) {
            int* hist = smem;          // [NBKT]
            int* gb   = smem + NBKT;   // [NBKT]
            for (int b = tid; b < NBKT; b += 256) hist[b] = 0;
            __syncthreads();
            int per = (NUM_INTER + nscat - 1) / nscat;
            int e0 = bid * per;
            int e1 = (e0 + per < NUM_INTER) ? e0 + per : NUM_INTER;
            // pass 1: per-bucket counts
            for (int e = e0 + tid; e < e1; e += 256) {
                int u  = P.iu[e];
                int it = NUM_USERS + P.ii[e];
                atomicAdd(&hist[u >> BSHIFT], 1);
                atomicAdd(&hist[it >> BSHIFT], 1);
            }
            __syncthreads();
            // one aggregated global atomic per (block,bucket); re-zero hist for pass 2
            for (int b = tid; b < NBKT; b += 256) {
                int c = hist[b];
                gb[b] = c ? atomicAdd(&P.cursor[b * 16], c) : 0;
                hist[b] = 0;
            }
            __syncthreads();
            // pass 2: re-read edges, assign in-block ranks, store refs
            for (int e = e0 + tid; e < e1; e += 256) {
                int u  = P.iu[e];
                int it = NUM_USERS + P.ii[e];
                int b0 = u >> BSHIFT;
                int r0 = atomicAdd(&hist[b0], 1);
                int s0 = gb[b0] + r0;
                if (s0 < CAP) P.pairs[(size_t)b0 * CAP + s0] = make_uint2((unsigned)u, (unsigned)it);
                int b1 = it >> BSHIFT;
                int r1 = atomicAdd(&hist[b1], 1);
                int s1 = gb[b1] + r1;
                if (s1 < CAP) P.pairs[(size_t)b1 * CAP + s1] = make_uint2((unsigned)it, (unsigned)u);
            }
        }
    }
    grid.sync();

    // ===== P2: per-bucket degrees/factors/lofs + flag neighbors of queried ========
    for (int b = bid; b < NBKT; b += nblk) {
        int* cnt = smem;            // [BNODES]
        int* sc  = smem + BNODES;   // [256]
        cnt[tid] = 0; cnt[tid + 256] = 0;
        __syncthreads();
        int n = P.cursor[b * 16]; if (n > CAP) n = CAP;
        const uint2* p = P.pairs + (size_t)b * CAP;
        for (int j = tid; j < n; j += 256) {
            uint2 pr = p[j];
            atomicAdd(&cnt[(int)pr.x & (BNODES - 1)], 1);
            if (P.qflag[pr.x]) P.flag[pr.y] = 1;   // neighbor-of-queried (replaces mark_k)
        }
        __syncthreads();
        int l0 = 2 * tid, l1 = 2 * tid + 1;
        int c0 = cnt[l0], c1 = cnt[l1];
        int p0 = (c0 + 3) & ~3, p1 = (c1 + 3) & ~3;
        int s = p0 + p1;
        sc[tid] = s;
        __syncthreads();
        for (int o = 1; o < 256; o <<= 1) {
            int x = (tid >= o) ? sc[tid - o] : 0;
            __syncthreads();
            sc[tid] += x;
            __syncthreads();
        }
        int excl = sc[tid] - s;
        int g0 = (b << BSHIFT) + l0;
        int g1 = g0 + 1;
        if (g0 < N_NODES) {
            P.deg[g0] = c0;
            float fd = (float)c0;
            P.dinv[g0] = (c0 > 0) ? (1.0f / sqrtf(fd)) : 0.0f;
            P.d2[g0]   = (c0 > 0) ? (1.0f / fd) : 0.0f;
            P.rcp[g0]  = (c0 > 0) ? sqrtf(fd) : 0.0f;
            P.lofs[g0] = excl;
        }
        if (g1 < N_NODES) {
            P.deg[g1] = c1;
            float fd = (float)c1;
            P.dinv[g1] = (c1 > 0) ? (1.0f / sqrtf(fd)) : 0.0f;
            P.d2[g1]   = (c1 > 0) ? (1.0f / fd) : 0.0f;
            P.rcp[g1]  = (c1 > 0) ? sqrtf(fd) : 0.0f;
            P.lofs[g1] = excl + p0;
        }
        if (tid == 255) P.bkt_pad[b] = sc[255];
        __syncthreads();
    }
    grid.sync();

    // ===== P3: block0: prefix over bucket totals + softmax + fp16 dummy rows ======
    if (bid == 0) {
        int i0 = 3 * tid;
        int v0 = (i0     < NBKT) ? P.bkt_pad[i0]     : 0;
        int v1 = (i0 + 1 < NBKT) ? P.bkt_pad[i0 + 1] : 0;
        int v2 = (i0 + 2 < NBKT) ? P.bkt_pad[i0 + 2] : 0;
        int s = v0 + v1 + v2;
        int* sc = smem;
        sc[tid] = s;
        __syncthreads();
        for (int o = 1; o < 256; o <<= 1) {
            int x = (tid >= o) ? sc[tid - o] : 0;
            __syncthreads();
            sc[tid] += x;
            __syncthreads();
        }
        int excl = sc[tid] - s;
        if (i0     < NBKT) P.bkt_base[i0]     = excl;
        if (i0 + 1 < NBKT) P.bkt_base[i0 + 1] = excl + v0;
        if (i0 + 2 < NBKT) P.bkt_base[i0 + 2] = excl + v0 + v1;
        if (tid == 255) P.row_start[N_NODES] = sc[255];
        if (tid < 96) {
            unsigned* pz = (tid < 32) ? (unsigned*)P.semb
                         : (tid < 64) ? (unsigned*)P.z1 : (unsigned*)P.z2;
            pz[(size_t)N_NODES * 32 + (tid & 31)] = 0u;
        }
        if (tid == 0) {
            float a = P.lw[0], b = P.lw[1], c = P.lw[2], d = P.lw[3];
            float m = fmaxf(fmaxf(a, b), fmaxf(c, d));
            float e0 = expf(a - m), e1 = expf(b - m), e2 = expf(c - m), e3 = expf(d - m);
            float sm = e0 + e1 + e2 + e3;
            P.w4[0] = e0 / sm; P.w4[1] = e1 / sm; P.w4[2] = e2 / sm; P.w4[3] = e3 / sm;
        }
    }
    grid.sync();

    // ===== P4: CSR build (bucket blocks) + fp16 prescaled emb (work-stolen) =======
    for (int b = bid; b < NBKT; b += nblk) {
        int* ofs  = smem;            // [BNODES]
        int* cnt2 = smem + BNODES;   // [BNODES]
        int base = P.bkt_base[b];
        int g0 = (b << BSHIFT) + tid;
        int g1 = g0 + 256;
        int o0 = (g0 < N_NODES) ? P.lofs[g0] : 0;
        int o1 = (g1 < N_NODES) ? P.lofs[g1] : 0;
        ofs[tid] = o0; ofs[tid + 256] = o1;
        cnt2[tid] = 0; cnt2[tid + 256] = 0;
        if (g0 < N_NODES) P.row_start[g0] = base + o0;
        if (g1 < N_NODES) P.row_start[g1] = base + o1;
        __syncthreads();
        int n = P.cursor[b * 16]; if (n > CAP) n = CAP;
        const uint2* p = P.pairs + (size_t)b * CAP;
        for (int j = tid; j < n; j += 256) {
            uint2 pr = p[j];
            int l = (int)pr.x & (BNODES - 1);
            int r = atomicAdd(&cnt2[l], 1);
            P.nbr[base + ofs[l] + r] = (int)pr.y;
        }
        __syncthreads();
    }
    // conv: semb[n] = dinv[n] * emb[n] (fp16), dynamically load-balanced
    while (true) {
        if (tid == 0) wsh = atomicAdd(P.work, 1);
        __syncthreads();
        int w = wsh;
        __syncthreads();
        if (w >= CONV_UNITS) break;
        int t = w * 256 + tid;
        int node = t >> 3;
        int q = t & 7;
        const float4* src = (node < NUM_USERS)
            ? (const float4*)P.ue + (size_t)node * 16
            : (const float4*)P.ie + (size_t)(node - NUM_USERS) * 16;
        float4 f0 = src[q * 2];
        float4 f1 = src[q * 2 + 1];
        float sdi = P.dinv[node];
        half8 h;
        h[0] = (_Float16)(sdi * f0.x); h[1] = (_Float16)(sdi * f0.y);
        h[2] = (_Float16)(sdi * f0.z); h[3] = (_Float16)(sdi * f0.w);
        h[4] = (_Float16)(sdi * f1.x); h[5] = (_Float16)(sdi * f1.y);
        h[6] = (_Float16)(sdi * f1.z); h[7] = (_Float16)(sdi * f1.w);
        ((half8*)P.semb)[(size_t)node * 8 + q] = h;
    }
    grid.sync();

    // ===== P5: layer-1 prop (full, pure fp16 sum-gather): z1 = d2 * sum semb ======
    for (int v0 = bid * 32; v0 < N_NODES; v0 += nblk * 32) {
        int node = v0 + (tid >> 3);
        int q = tid & 7;
        if (node < N_NODES) {
            int beg = P.row_start[node], end = P.row_start[node + 1];
            int lim = beg + P.deg[node];
            const half8* src = (const half8*)P.semb;
            float a0=0.f,a1=0.f,a2=0.f,a3=0.f,a4=0.f,a5=0.f,a6=0.f,a7=0.f;
            for (int j = beg; j < end; j += 8) {
                vint4 na  = __builtin_nontemporal_load((const vint4*)(P.nbr + j));
                vint4 nb4 = __builtin_nontemporal_load((const vint4*)(P.nbr + j + 4));
                #pragma unroll
                for (int k = 0; k < 8; ++k) {
                    int id = (j + k < lim) ? ((k < 4) ? na[k] : nb4[k - 4]) : N_NODES;
                    half8 h = src[(size_t)id * 8 + q];
                    a0 += (float)h[0]; a1 += (float)h[1]; a2 += (float)h[2]; a3 += (float)h[3];
                    a4 += (float)h[4]; a5 += (float)h[5]; a6 += (float)h[6]; a7 += (float)h[7];
                }
            }
            float sd = P.d2[node];
            half8 r;
            r[0] = (_Float16)(sd * a0); r[1] = (_Float16)(sd * a1);
            r[2] = (_Float16)(sd * a2); r[3] = (_Float16)(sd * a3);
            r[4] = (_Float16)(sd * a4); r[5] = (_Float16)(sd * a5);
            r[6] = (_Float16)(sd * a6); r[7] = (_Float16)(sd * a7);
            __builtin_nontemporal_store(r, (half8*)P.z1 + (size_t)node * 8 + q);
        }
    }
    grid.sync();

    // ===== P6: layer-2 prop (flag-masked): z2 = d2 * sum z1 =======================
    for (int v0 = bid * 32; v0 < N_NODES; v0 += nblk * 32) {
        int node = v0 + (tid >> 3);
        int q = tid & 7;
        if (node < N_NODES && P.flag[node]) {
            int beg = P.row_start[node], end = P.row_start[node + 1];
            int lim = beg + P.deg[node];
            const half8* src = (const half8*)P.z1;
            float a0=0.f,a1=0.f,a2=0.f,a3=0.f,a4=0.f,a5=0.f,a6=0.f,a7=0.f;
            for (int j = beg; j < end; j += 8) {
                vint4 na  = __builtin_nontemporal_load((const vint4*)(P.nbr + j));
                vint4 nb4 = __builtin_nontemporal_load((const vint4*)(P.nbr + j + 4));
                #pragma unroll
                for (int k = 0; k < 8; ++k) {
                    int id = (j + k < lim) ? ((k < 4) ? na[k] : nb4[k - 4]) : N_NODES;
                    half8 h = src[(size_t)id * 8 + q];
                    a0 += (float)h[0]; a1 += (float)h[1]; a2 += (float)h[2]; a3 += (float)h[3];
                    a4 += (float)h[4]; a5 += (float)h[5]; a6 += (float)h[6]; a7 += (float)h[7];
                }
            }
            float sd = P.d2[node];
            half8 r;
            r[0] = (_Float16)(sd * a0); r[1] = (_Float16)(sd * a1);
            r[2] = (_Float16)(sd * a2); r[3] = (_Float16)(sd * a3);
            r[4] = (_Float16)(sd * a4); r[5] = (_Float16)(sd * a5);
            r[6] = (_Float16)(sd * a6); r[7] = (_Float16)(sd * a7);
            __builtin_nontemporal_store(r, (half8*)P.z2 + (size_t)node * 8 + q);
        }
    }
    grid.sync();

    // ===== P7: fused epilogue: layer-3 pull at queried + layers 0-2 + dot =========
    for (int s0 = g; s0 < BATCH * 16; s0 += gt) {
        int slot = s0 >> 4;
        int within = s0 & 15;
        int side = within >> 3;
        int q = within & 7;

        int node;
        const float4* erow;
        if (side == 0) {
            int u = P.uid[slot];
            node = u;
            erow = (const float4*)P.ue + (size_t)u * 16;
        } else {
            int ii_ = P.iid[slot];
            node = NUM_USERS + ii_;
            erow = (const float4*)P.ie + (size_t)ii_ * 16;
        }

        float w0 = P.w4[0], w1 = P.w4[1], w2 = P.w4[2], w3 = P.w4[3];
        int beg = P.row_start[node], end = P.row_start[node + 1];
        int lim = beg + P.deg[node];
        const half8* z2v = (const half8*)P.z2;

        float a0=0.f,a1=0.f,a2=0.f,a3=0.f,a4=0.f,a5=0.f,a6=0.f,a7=0.f;
        for (int j = beg; j < end; j += 8) {
            vint4 na  = __builtin_nontemporal_load((const vint4*)(P.nbr + j));
            vint4 nb4 = __builtin_nontemporal_load((const vint4*)(P.nbr + j + 4));
            #pragma unroll
            for (int k = 0; k < 8; ++k) {
                int id = (j + k < lim) ? ((k < 4) ? na[k] : nb4[k - 4]) : N_NODES;
                half8 h = z2v[(size_t)id * 8 + q];
                a0 += (float)h[0]; a1 += (float)h[1]; a2 += (float)h[2]; a3 += (float)h[3];
                a4 += (float)h[4]; a5 += (float)h[5]; a6 += (float)h[6]; a7 += (float)h[7];
            }
        }

        float r  = P.rcp[node];
        float di = P.dinv[node];
        float e[8];
        *reinterpret_cast<float4*>(&e[0]) = erow[q * 2];
        *reinterpret_cast<float4*>(&e[4]) = erow[q * 2 + 1];
        half8 h1 = ((const half8*)P.z1)[(size_t)node * 8 + q];
        half8 h2 = z2v[(size_t)node * 8 + q];
        float acc[8] = {a0, a1, a2, a3, a4, a5, a6, a7};

        float f[8];
        #pragma unroll
        for (int d = 0; d < 8; ++d)
            f[d] = w0 * e[d] + r * (w1 * (float)h1[d] + w2 * (float)h2[d]) + w3 * di * acc[d];

        float pr = 0.f;
        #pragma unroll
        for (int d = 0; d < 8; ++d) {
            float o = __shfl_xor(f[d], 8);   // partner side, same dims
            pr += f[d] * o;
        }
        pr += __shfl_xor(pr, 1);
        pr += __shfl_xor(pr, 2);
        pr += __shfl_xor(pr, 4);

        if (within == 0) P.out[slot] = pr;
    }
}

// ---------------- launch ----------------

extern "C" void kernel_launch(void* const* d_in, const int* in_sizes, int n_in,
                              void* d_out, int out_size, void* d_ws, size_t ws_size,
                              hipStream_t stream) {
    char* base = (char*)d_ws;
    size_t off = 0;
    auto alloc = [&](size_t bytes) -> char* {
        char* p = base + off;
        off = (off + bytes + 255) & ~(size_t)255;
        return p;
    };

    Params P;
    P.ue  = (const float*)d_in[0];
    P.ie  = (const float*)d_in[1];
    P.lw  = (const float*)d_in[2];
    P.iu  = (const int*)d_in[3];
    P.ii  = (const int*)d_in[4];
    P.uid = (const int*)d_in[5];
    P.iid = (const int*)d_in[6];
    P.out = (float*)d_out;

    P.w4        = (float*)    alloc(4 * sizeof(float));
    P.deg       = (int*)      alloc((size_t)N_NODES * sizeof(int));
    P.dinv      = (float*)    alloc((size_t)N_NODES * sizeof(float));
    P.d2        = (float*)    alloc((size_t)N_NODES * sizeof(float));
    P.rcp       = (float*)    alloc((size_t)N_NODES * sizeof(float));
    P.lofs      = (int*)      alloc((size_t)N_NODES * sizeof(int));
    P.row_start = (int*)      alloc(((size_t)N_NODES + 1) * sizeof(int));
    P.bkt_pad   = (int*)      alloc((size_t)NBKT * sizeof(int));
    P.bkt_base  = (int*)      alloc((size_t)NBKT * sizeof(int));
    P.flag      = (int*)      alloc((size_t)N_NODES * sizeof(int));
    P.qflag     = (unsigned char*)alloc((size_t)N_NODES + 4);
    P.work      = (int*)      alloc(256);
    P.cursor    = (int*)      alloc((size_t)NBKT * 16 * sizeof(int));
    P.pairs     = (uint2*)    alloc((size_t)NBKT * CAP * sizeof(uint2));
    P.nbr       = (int*)      alloc((size_t)MAX_SLOTS * sizeof(int));
    P.semb      = (_Float16*) alloc(((size_t)N_NODES + 1) * EMB * sizeof(_Float16));
    P.z1        = (_Float16*) alloc(((size_t)N_NODES + 1) * EMB * sizeof(_Float16));
    P.z2        = (_Float16*) alloc(((size_t)N_NODES + 1) * EMB * sizeof(_Float16));

    // co-residency-safe grid size (queried once; host query only, capture-safe)
    static int g_grid = 0;
    if (g_grid == 0) {
        int dev = 0;
        hipGetDevice(&dev);
        hipDeviceProp_t prop{};
        hipGetDeviceProperties(&prop, dev);
        int bpc = 0;
        hipOccupancyMaxActiveBlocksPerMultiprocessor(&bpc, (const void*)mega_k, 256, 0);
        if (bpc < 1) bpc = 1;
        long gg = (long)bpc * (long)prop.multiProcessorCount;
        if (gg > 2048) gg = 2048;
        if (gg < 1) gg = 1;
        g_grid = (int)gg;
    }

    void* args[] = { (void*)&P };
    hipLaunchCooperativeKernel((const void*)mega_k, dim3(g_grid), dim3(256),
                               args, 0, stream);
}

// Round 4
// 271.886 us; speedup vs baseline: 3.0947x; 3.0947x over previous
//
#include <hip/hip_runtime.h>
#include <math.h>

#define NUM_USERS 100000
#define NUM_ITEMS 200000
#define N_NODES   300000   // NUM_USERS + NUM_ITEMS
#define EMB       64
#define NUM_INTER 1000000
#define MAX_SLOTS (2 * NUM_INTER + 3 * N_NODES + 16)   // rows padded to x4
#define BATCH     16384

// ---- bucketed CSR builder geometry ----
#define BSHIFT 9
#define BNODES 512
#define NBKT   ((N_NODES + BNODES - 1) / BNODES)    // 586
#define CAP    6144                                 // refs per bucket (max expected ~5400)
#define EDGES_PER_BLOCK 4096                        // 8192 refs per scatter block
#define AB_BLOCKS ((NUM_INTER + EDGES_PER_BLOCK - 1) / EDGES_PER_BLOCK)   // 245
#define QMARK_BLOCKS ((BATCH * 2) / 256)            // 128

#define CONV_BLOCKS ((N_NODES * 8 + 255) / 256)  // 9375
#define PROP_BLOCKS ((N_NODES * 8 + 255) / 256)  // 9375

typedef int      vint4 __attribute__((ext_vector_type(4)));
typedef _Float16 half8 __attribute__((ext_vector_type(8)));

// pair code: (local_node_in_bucket << 19) | partner   (local<512, partner<2^19)
#define PMASK 0x7FFFFu

// ---------- pass A: qflag of queried (first 128 blocks) + bucket scatter ----------
// LDS atomics assign block-local ranks; ONE aggregated global atomic per
// (block,bucket) on a 64B-padded cursor replaces 2M far atomics.
__global__ __launch_bounds__(256) void bucket_scatter_k(
        const int* __restrict__ iu, const int* __restrict__ ii,
        const int* __restrict__ uid, const int* __restrict__ iid,
        int* __restrict__ cursor /*stride 16 ints*/, unsigned* __restrict__ pairs,
        unsigned char* __restrict__ qflag, int* __restrict__ flag) {
    int tid = threadIdx.x;
    if (blockIdx.x < QMARK_BLOCKS) {
        int t = blockIdx.x * 256 + tid;               // < BATCH*2 exactly
        int node = (t & 1) ? (NUM_USERS + iid[t >> 1]) : uid[t >> 1];
        qflag[node] = 1;
        flag[node]  = 1;                              // queried nodes need z2 too
        return;
    }
    __shared__ int hist[NBKT];
    __shared__ int gbase[NBKT];
    int bid = blockIdx.x - QMARK_BLOCKS;
    for (int b = tid; b < NBKT; b += 256) hist[b] = 0;
    __syncthreads();

    int e0 = bid * EDGES_PER_BLOCK;
    int u[16], it[16];
    unsigned pk[32];
    #pragma unroll
    for (int k = 0; k < 16; ++k) {
        int e = e0 + k * 256 + tid;
        bool v = (e < NUM_INTER);
        u[k]  = v ? iu[e] : -1;
        it[k] = v ? (NUM_USERS + ii[e]) : -1;
    }
    #pragma unroll
    for (int k = 0; k < 16; ++k) {
        if (u[k] >= 0) {
            int b0 = u[k] >> BSHIFT;
            int r0 = atomicAdd(&hist[b0], 1);
            pk[2 * k] = ((unsigned)b0 << 13) | (unsigned)r0;    // lrank < 8192
            int b1 = it[k] >> BSHIFT;
            int r1 = atomicAdd(&hist[b1], 1);
            pk[2 * k + 1] = ((unsigned)b1 << 13) | (unsigned)r1;
        }
    }
    __syncthreads();
    for (int b = tid; b < NBKT; b += 256) {
        int c = hist[b];
        if (c) gbase[b] = atomicAdd(&cursor[b * 16], c);
    }
    __syncthreads();
    #pragma unroll
    for (int k = 0; k < 16; ++k) {
        if (u[k] >= 0) {
            unsigned p0 = pk[2 * k];
            int b0 = (int)(p0 >> 13);
            int s0 = gbase[b0] + (int)(p0 & 0x1fffu);
            if (s0 < CAP)
                pairs[(size_t)b0 * CAP + s0] =
                    ((unsigned)(u[k] & (BNODES - 1)) << 19) | (unsigned)it[k];
            unsigned p1 = pk[2 * k + 1];
            int b1 = (int)(p1 >> 13);
            int s1 = gbase[b1] + (int)(p1 & 0x1fffu);
            if (s1 < CAP)
                pairs[(size_t)b1 * CAP + s1] =
                    ((unsigned)(it[k] & (BNODES - 1)) << 19) | (unsigned)u[k];
        }
    }
}

// ---------- pass B: per-bucket degrees + factors + padded local offsets ----------
// Also flags neighbors-of-queried while streaming the pairs (replaces mark_k).
__global__ __launch_bounds__(256) void bucket_deg_k(
        const int* __restrict__ cursor, const unsigned* __restrict__ pairs,
        const unsigned char* __restrict__ qflag, int* __restrict__ flag,
        int* __restrict__ deg, float* __restrict__ dinv, float* __restrict__ d2,
        float* __restrict__ rcp, int* __restrict__ lofs, int* __restrict__ bkt_padded) {
    __shared__ int cnt[BNODES];
    __shared__ int sc[256];
    __shared__ unsigned qf[BNODES / 4];   // 512 qflag bytes for this bucket
    int b = blockIdx.x, tid = threadIdx.x;
    cnt[tid] = 0; cnt[tid + 256] = 0;
    if (tid < BNODES / 4)
        qf[tid] = ((const unsigned*)(qflag + ((size_t)b << BSHIFT)))[tid];
    __syncthreads();
    int n = cursor[b * 16]; if (n > CAP) n = CAP;
    const unsigned* p = pairs + (size_t)b * CAP;
    const unsigned char* qfb = (const unsigned char*)qf;
    for (int j = tid; j < n; j += 256) {
        unsigned code = p[j];
        int l = (int)(code >> 19);
        atomicAdd(&cnt[l], 1);
        if (qfb[l]) flag[code & PMASK] = 1;   // neighbor-of-queried
    }
    __syncthreads();

    int l0 = 2 * tid, l1 = 2 * tid + 1;
    int c0 = cnt[l0], c1 = cnt[l1];
    int p0 = (c0 + 3) & ~3, p1 = (c1 + 3) & ~3;
    int s = p0 + p1;
    sc[tid] = s;
    __syncthreads();
    for (int o = 1; o < 256; o <<= 1) {
        int x = (tid >= o) ? sc[tid - o] : 0;
        __syncthreads();
        sc[tid] += x;
        __syncthreads();
    }
    int excl = sc[tid] - s;
    int g0 = (b << BSHIFT) + l0;
    int g1 = g0 + 1;
    if (g0 < N_NODES) {
        deg[g0] = c0;
        float fd = (float)c0;
        dinv[g0] = (c0 > 0) ? (1.0f / sqrtf(fd)) : 0.0f;
        d2[g0]   = (c0 > 0) ? (1.0f / fd) : 0.0f;
        rcp[g0]  = (c0 > 0) ? sqrtf(fd) : 0.0f;
        lofs[g0] = excl;
    }
    if (g1 < N_NODES) {
        deg[g1] = c1;
        float fd = (float)c1;
        dinv[g1] = (c1 > 0) ? (1.0f / sqrtf(fd)) : 0.0f;
        d2[g1]   = (c1 > 0) ? (1.0f / fd) : 0.0f;
        rcp[g1]  = (c1 > 0) ? sqrtf(fd) : 0.0f;
        lofs[g1] = excl + p0;
    }
    if (tid == 255) bkt_padded[b] = sc[255];
}

// ---------- pass C: prefix over bucket totals + softmax + fp16 dummy-row zeroing ----------
__global__ void csr_mid_k(const int* __restrict__ bkt_padded, int* __restrict__ bkt_base,
                          int* __restrict__ row_start,
                          const float* __restrict__ lw, float* __restrict__ w,
                          _Float16* __restrict__ semb, _Float16* __restrict__ z1,
                          _Float16* __restrict__ z2) {
    __shared__ int lds[1024];
    int t = threadIdx.x;
    int v = (t < NBKT) ? bkt_padded[t] : 0;
    lds[t] = v;
    __syncthreads();
    for (int o = 1; o < 1024; o <<= 1) {
        int x = (t >= o) ? lds[t - o] : 0;
        __syncthreads();
        lds[t] += x;
        __syncthreads();
    }
    if (t < NBKT) bkt_base[t] = lds[t] - v;              // exclusive
    if (t == 1023) row_start[N_NODES] = lds[1023];       // grand total (x4-aligned)
    if (t < 96) {
        unsigned* p = (t < 32) ? (unsigned*)semb : (t < 64) ? (unsigned*)z1 : (unsigned*)z2;
        p[(size_t)N_NODES * 32 + (t & 31)] = 0u;
    }
    if (t == 0) {
        float a = lw[0], b = lw[1], c = lw[2], d = lw[3];
        float m = fmaxf(fmaxf(a, b), fmaxf(c, d));
        float e0 = expf(a - m), e1 = expf(b - m), e2 = expf(c - m), e3 = expf(d - m);
        float sm = e0 + e1 + e2 + e3;
        w[0] = e0 / sm; w[1] = e1 / sm; w[2] = e2 / sm; w[3] = e3 / sm;
    }
}

// ---------- pass D: write row_start + scatter partners into CSR; extra blocks: fp16 conv ----------
// semb[n] = dinv[n] * emb[n]  (unified user|item table, fp16 rows of 128 B)
__global__ __launch_bounds__(256) void bucket_build_k(
        const int* __restrict__ cursor, const unsigned* __restrict__ pairs,
        const int* __restrict__ bkt_base, const int* __restrict__ lofs,
        int* __restrict__ row_start, int* __restrict__ nbr,
        const float* __restrict__ dinv,
        const float* __restrict__ ue, const float* __restrict__ ie,
        _Float16* __restrict__ semb) {
    int bid = blockIdx.x;
    int tid = threadIdx.x;
    if (bid >= NBKT) {
        int t = (bid - NBKT) * 256 + tid;
        int node = t >> 3;
        int q = t & 7;
        if (node >= N_NODES) return;
        const float4* src = (node < NUM_USERS)
            ? (const float4*)ue + (size_t)node * 16
            : (const float4*)ie + (size_t)(node - NUM_USERS) * 16;
        float4 f0 = src[q * 2];
        float4 f1 = src[q * 2 + 1];
        float s = dinv[node];
        half8 h;
        h[0] = (_Float16)(s * f0.x); h[1] = (_Float16)(s * f0.y);
        h[2] = (_Float16)(s * f0.z); h[3] = (_Float16)(s * f0.w);
        h[4] = (_Float16)(s * f1.x); h[5] = (_Float16)(s * f1.y);
        h[6] = (_Float16)(s * f1.z); h[7] = (_Float16)(s * f1.w);
        ((half8*)semb)[(size_t)node * 8 + q] = h;
        return;
    }
    __shared__ int ofs[BNODES];
    __shared__ int cnt2[BNODES];
    int b = bid;
    int base = bkt_base[b];
    {
        int g0 = (b << BSHIFT) + tid;
        int g1 = g0 + 256;
        int o0 = (g0 < N_NODES) ? lofs[g0] : 0;
        int o1 = (g1 < N_NODES) ? lofs[g1] : 0;
        ofs[tid] = o0; ofs[tid + 256] = o1;
        cnt2[tid] = 0; cnt2[tid + 256] = 0;
        if (g0 < N_NODES) row_start[g0] = base + o0;
        if (g1 < N_NODES) row_start[g1] = base + o1;
    }
    __syncthreads();
    int n = cursor[b * 16]; if (n > CAP) n = CAP;
    const unsigned* p = pairs + (size_t)b * CAP;
    for (int j = tid; j < n; j += 256) {
        unsigned code = p[j];
        int l = (int)(code >> 19);
        int r = atomicAdd(&cnt2[l], 1);
        nbr[base + ofs[l] + r] = (int)(code & PMASK);
    }
}

// ---------- prop layer 1 (full, pure fp16 sum-gather): z1 = d2 * sum semb ----------
__global__ void prop_first_k(const int* __restrict__ row_start, const int* __restrict__ nbr,
                             const int* __restrict__ deg, const float* __restrict__ d2,
                             const _Float16* __restrict__ semb, _Float16* __restrict__ z1) {
    int t = blockIdx.x * blockDim.x + threadIdx.x;
    int node = t >> 3;
    int q = t & 7;
    if (node >= N_NODES) return;
    int beg = row_start[node], end = row_start[node + 1];
    int lim = beg + deg[node];
    const half8* src = (const half8*)semb;
    float a0 = 0.f, a1 = 0.f, a2 = 0.f, a3 = 0.f, a4 = 0.f, a5 = 0.f, a6 = 0.f, a7 = 0.f;
    for (int j = beg; j < end; j += 8) {
        vint4 na = __builtin_nontemporal_load((const vint4*)(nbr + j));
        vint4 nb = __builtin_nontemporal_load((const vint4*)(nbr + j + 4));
        #pragma unroll
        for (int k = 0; k < 8; ++k) {
            int id = (j + k < lim) ? ((k < 4) ? na[k] : nb[k - 4]) : N_NODES;
            half8 h = src[(size_t)id * 8 + q];
            a0 += (float)h[0]; a1 += (float)h[1]; a2 += (float)h[2]; a3 += (float)h[3];
            a4 += (float)h[4]; a5 += (float)h[5]; a6 += (float)h[6]; a7 += (float)h[7];
        }
    }
    float s = d2[node];
    half8 r;
    r[0] = (_Float16)(s * a0); r[1] = (_Float16)(s * a1);
    r[2] = (_Float16)(s * a2); r[3] = (_Float16)(s * a3);
    r[4] = (_Float16)(s * a4); r[5] = (_Float16)(s * a5);
    r[6] = (_Float16)(s * a6); r[7] = (_Float16)(s * a7);
    __builtin_nontemporal_store(r, (half8*)z1 + (size_t)node * 8 + q);
}

// ---------- prop layer 2 (node-ordered, flag-masked, fp16): z2 = d2 * sum z1 ----------
__global__ void prop_masked_k(const int* __restrict__ row_start, const int* __restrict__ nbr,
                              const int* __restrict__ deg, const float* __restrict__ d2,
                              const int* __restrict__ flag,
                              const _Float16* __restrict__ in, _Float16* __restrict__ out) {
    int t = blockIdx.x * blockDim.x + threadIdx.x;
    int node = t >> 3;
    int q = t & 7;
    if (node >= N_NODES) return;
    if (!flag[node]) return;   // z2 never read at unflagged nodes
    int beg = row_start[node], end = row_start[node + 1];
    int lim = beg + deg[node];
    const half8* src = (const half8*)in;
    float a0 = 0.f, a1 = 0.f, a2 = 0.f, a3 = 0.f, a4 = 0.f, a5 = 0.f, a6 = 0.f, a7 = 0.f;
    for (int j = beg; j < end; j += 8) {
        vint4 na = __builtin_nontemporal_load((const vint4*)(nbr + j));
        vint4 nb = __builtin_nontemporal_load((const vint4*)(nbr + j + 4));
        #pragma unroll
        for (int k = 0; k < 8; ++k) {
            int id = (j + k < lim) ? ((k < 4) ? na[k] : nb[k - 4]) : N_NODES;
            half8 h = src[(size_t)id * 8 + q];
            a0 += (float)h[0]; a1 += (float)h[1]; a2 += (float)h[2]; a3 += (float)h[3];
            a4 += (float)h[4]; a5 += (float)h[5]; a6 += (float)h[6]; a7 += (float)h[7];
        }
    }
    float s = d2[node];
    half8 r;
    r[0] = (_Float16)(s * a0); r[1] = (_Float16)(s * a1);
    r[2] = (_Float16)(s * a2); r[3] = (_Float16)(s * a3);
    r[4] = (_Float16)(s * a4); r[5] = (_Float16)(s * a5);
    r[6] = (_Float16)(s * a6); r[7] = (_Float16)(s * a7);
    __builtin_nontemporal_store(r, (half8*)out + (size_t)node * 8 + q);
}

// ---------- fused epilogue: layer-3 pull at queried nodes + layers 0-2 + dot ----------
// 16 lanes per (u,i) pair: 8 lanes user side, 8 lanes item side, 8 dims/lane
__global__ void fused_score_k(const int* __restrict__ row_start, const int* __restrict__ nbr,
                              const int* __restrict__ deg,
                              const float* __restrict__ dinv, const float* __restrict__ rcp,
                              const float* __restrict__ ue, const float* __restrict__ ie,
                              const _Float16* __restrict__ z1, const _Float16* __restrict__ z2,
                              const int* __restrict__ uid, const int* __restrict__ iid,
                              const float* __restrict__ w4, float* __restrict__ out) {
    int t = blockIdx.x * blockDim.x + threadIdx.x;
    int slot = t >> 4;
    if (slot >= BATCH) return;
    int within = t & 15;
    int side = within >> 3;
    int q = within & 7;

    int node;
    const float4* erow;
    if (side == 0) {
        int u = uid[slot];
        node = u;
        erow = (const float4*)ue + (size_t)u * 16;
    } else {
        int ii_ = iid[slot];
        node = NUM_USERS + ii_;
        erow = (const float4*)ie + (size_t)ii_ * 16;
    }

    float w0 = w4[0], w1 = w4[1], w2 = w4[2], w3 = w4[3];
    int beg = row_start[node], end = row_start[node + 1];
    int lim = beg + deg[node];
    const half8* z2v = (const half8*)z2;

    float a0 = 0.f, a1 = 0.f, a2 = 0.f, a3 = 0.f, a4 = 0.f, a5 = 0.f, a6 = 0.f, a7 = 0.f;
    for (int j = beg; j < end; j += 8) {
        vint4 na = __builtin_nontemporal_load((const vint4*)(nbr + j));
        vint4 nb = __builtin_nontemporal_load((const vint4*)(nbr + j + 4));
        #pragma unroll
        for (int k = 0; k < 8; ++k) {
            int id = (j + k < lim) ? ((k < 4) ? na[k] : nb[k - 4]) : N_NODES;
            half8 h = z2v[(size_t)id * 8 + q];
            a0 += (float)h[0]; a1 += (float)h[1]; a2 += (float)h[2]; a3 += (float)h[3];
            a4 += (float)h[4]; a5 += (float)h[5]; a6 += (float)h[6]; a7 += (float)h[7];
        }
    }

    float r  = rcp[node];
    float di = dinv[node];
    float e[8];
    *reinterpret_cast<float4*>(&e[0]) = erow[q * 2];
    *reinterpret_cast<float4*>(&e[4]) = erow[q * 2 + 1];
    half8 h1 = ((const half8*)z1)[(size_t)node * 8 + q];
    half8 h2 = z2v[(size_t)node * 8 + q];
    float acc[8] = {a0, a1, a2, a3, a4, a5, a6, a7};

    float f[8];
    #pragma unroll
    for (int d = 0; d < 8; ++d)
        f[d] = w0 * e[d] + r * (w1 * (float)h1[d] + w2 * (float)h2[d]) + w3 * di * acc[d];

    float p = 0.f;
    #pragma unroll
    for (int d = 0; d < 8; ++d) {
        float o = __shfl_xor(f[d], 8);   // partner side, same dims
        p += f[d] * o;
    }
    p += __shfl_xor(p, 1);
    p += __shfl_xor(p, 2);
    p += __shfl_xor(p, 4);

    if (within == 0) out[slot] = p;
}

// ---------- launch ----------

extern "C" void kernel_launch(void* const* d_in, const int* in_sizes, int n_in,
                              void* d_out, int out_size, void* d_ws, size_t ws_size,
                              hipStream_t stream) {
    const float* user_emb = (const float*)d_in[0];
    const float* item_emb = (const float*)d_in[1];
    const float* layer_w  = (const float*)d_in[2];
    const int*   inter_u  = (const int*)d_in[3];
    const int*   inter_i  = (const int*)d_in[4];
    const int*   user_ids = (const int*)d_in[5];
    const int*   item_ids = (const int*)d_in[6];
    float* out = (float*)d_out;

    char* base = (char*)d_ws;
    size_t off = 0;
    auto alloc = [&](size_t bytes) -> char* {
        char* p = base + off;
        off = (off + bytes + 255) & ~(size_t)255;
        return p;
    };
    float*    w4        = (float*)    alloc(4 * sizeof(float));
    int*      deg       = (int*)      alloc((size_t)N_NODES * sizeof(int));
    float*    dinv      = (float*)    alloc((size_t)N_NODES * sizeof(float));
    float*    d2        = (float*)    alloc((size_t)N_NODES * sizeof(float));
    float*    rcp       = (float*)    alloc((size_t)N_NODES * sizeof(float));
    int*      lofs      = (int*)      alloc((size_t)N_NODES * sizeof(int));
    int*      row_start = (int*)      alloc(((size_t)N_NODES + 1) * sizeof(int));
    int*      bkt_pad   = (int*)      alloc((size_t)NBKT * sizeof(int));
    int*      bkt_base  = (int*)      alloc((size_t)NBKT * sizeof(int));
    // zeroed region: flag + qflag + cursor (adjacent; single memset)
    int*           flag   = (int*)          alloc((size_t)N_NODES * sizeof(int));
    unsigned char* qflag  = (unsigned char*)alloc((size_t)N_NODES + 512);
    int*           cursor = (int*)          alloc((size_t)NBKT * 16 * sizeof(int));
    unsigned* pairs     = (unsigned*) alloc((size_t)NBKT * CAP * sizeof(unsigned));
    int*      csr_nbr   = (int*)      alloc((size_t)MAX_SLOTS * sizeof(int));
    _Float16* semb      = (_Float16*) alloc(((size_t)N_NODES + 1) * EMB * sizeof(_Float16));
    _Float16* zA        = (_Float16*) alloc(((size_t)N_NODES + 1) * EMB * sizeof(_Float16));
    _Float16* zB        = (_Float16*) alloc(((size_t)N_NODES + 1) * EMB * sizeof(_Float16));

    // 1. zero flag + qflag + bucket cursors (adjacent allocations, single memset)
    size_t span = (size_t)((char*)cursor - (char*)flag) + (size_t)NBKT * 16 * sizeof(int);
    hipMemsetAsync(flag, 0, span, stream);

    // 2. qflag of queried (128 blocks) + scatter refs into bucket regions
    bucket_scatter_k<<<QMARK_BLOCKS + AB_BLOCKS, 256, 0, stream>>>(
        inter_u, inter_i, user_ids, item_ids, cursor, pairs, qflag, flag);

    // 3. per-bucket degrees + factors + lofs; flags neighbors-of-queried in-stream
    bucket_deg_k<<<NBKT, 256, 0, stream>>>(
        cursor, pairs, qflag, flag, deg, dinv, d2, rcp, lofs, bkt_pad);

    // 4. prefix over bucket totals + softmax + fp16 dummy-row zeroing
    csr_mid_k<<<1, 1024, 0, stream>>>(bkt_pad, bkt_base, row_start, layer_w, w4, semb, zB, zA);

    // 5. row_start + CSR scatter (LDS ranks); extra blocks: dinv-prescaled fp16 emb table
    bucket_build_k<<<NBKT + CONV_BLOCKS, 256, 0, stream>>>(
        cursor, pairs, bkt_base, lofs, row_start, csr_nbr, dinv, user_emb, item_emb, semb);

    // 6. layer 1 full (pure fp16 sum-gather): zB = z1
    prop_first_k<<<PROP_BLOCKS, 256, 0, stream>>>(
        row_start, csr_nbr, deg, d2, semb, zB);

    // 7. layer 2 flag-masked, node-ordered, fp16: zA = z2
    prop_masked_k<<<PROP_BLOCKS, 256, 0, stream>>>(
        row_start, csr_nbr, deg, d2, flag, zB, zA);

    // 8. fused: layer-3 pull at queried nodes + layer 0-2 terms + dot product
    fused_score_k<<<(BATCH * 16 + 255) / 256, 256, 0, stream>>>(
        row_start, csr_nbr, deg, dinv, rcp, user_emb, item_emb,
        zB /*z1*/, zA /*z2*/, user_ids, item_ids, w4, out);
}

// Round 5
// 267.475 us; speedup vs baseline: 3.1458x; 1.0165x over previous
//
#include <hip/hip_runtime.h>
#include <math.h>

#define NUM_USERS 100000
#define NUM_ITEMS 200000
#define N_NODES   300000   // NUM_USERS + NUM_ITEMS
#define EMB       64
#define NUM_INTER 1000000
#define BATCH     16384

// ---- bucketed CSR builder geometry ----
#define BSHIFT 9
#define BNODES 512
#define NBKT   ((N_NODES + BNODES - 1) / BNODES)    // 586
#define CAP    6144       // refs per bucket (max expected ~5400)
#define RSHIFT 13         // fixed nbr region per bucket: 8192 slots (max padded use 7680)
#define RSLOTS (1 << RSHIFT)
#define EDGES_PER_BLOCK 4096                        // 8192 refs per scatter block
#define AB_BLOCKS ((NUM_INTER + EDGES_PER_BLOCK - 1) / EDGES_PER_BLOCK)   // 245
#define QMARK_BLOCKS ((BATCH * 2) / 256)            // 128

#define PROP_BLOCKS ((N_NODES * 8 + 255) / 256)  // 9375

typedef int      vint4 __attribute__((ext_vector_type(4)));
typedef _Float16 half8 __attribute__((ext_vector_type(8)));

// pair code: (local_node_in_bucket << 19) | partner   (local<512, partner<2^19)
#define PMASK 0x7FFFFu

// ---------- pass A: qmark (128 blk) + misc (1 blk: softmax + dummy rows) + scatter ----------
__global__ __launch_bounds__(256) void bucket_scatter_k(
        const int* __restrict__ iu, const int* __restrict__ ii,
        const int* __restrict__ uid, const int* __restrict__ iid,
        int* __restrict__ cursor /*stride 16 ints*/, unsigned* __restrict__ pairs,
        unsigned char* __restrict__ qflag, unsigned char* __restrict__ flag,
        const float* __restrict__ lw, float* __restrict__ w4,
        _Float16* __restrict__ semb, _Float16* __restrict__ z1, _Float16* __restrict__ z2) {
    int tid = threadIdx.x;
    if (blockIdx.x < QMARK_BLOCKS) {
        int t = blockIdx.x * 256 + tid;               // < BATCH*2 exactly
        int node = (t & 1) ? (NUM_USERS + iid[t >> 1]) : uid[t >> 1];
        qflag[node] = 1;
        flag[node]  = 1;                              // queried nodes need z2 too
        return;
    }
    if (blockIdx.x == QMARK_BLOCKS) {
        // misc: zero dummy row (idx N_NODES, 128 B) of each fp16 table + softmax(lw)
        if (tid < 96) {
            unsigned* p = (tid < 32) ? (unsigned*)semb : (tid < 64) ? (unsigned*)z1 : (unsigned*)z2;
            p[(size_t)N_NODES * 32 + (tid & 31)] = 0u;
        }
        if (tid == 0) {
            float a = lw[0], b = lw[1], c = lw[2], d = lw[3];
            float m = fmaxf(fmaxf(a, b), fmaxf(c, d));
            float e0 = expf(a - m), e1 = expf(b - m), e2 = expf(c - m), e3 = expf(d - m);
            float sm = e0 + e1 + e2 + e3;
            w4[0] = e0 / sm; w4[1] = e1 / sm; w4[2] = e2 / sm; w4[3] = e3 / sm;
        }
        return;
    }
    __shared__ int hist[NBKT];
    __shared__ int gbase[NBKT];
    int bid = blockIdx.x - QMARK_BLOCKS - 1;
    for (int b = tid; b < NBKT; b += 256) hist[b] = 0;
    __syncthreads();

    int e0 = bid * EDGES_PER_BLOCK;
    int u[16], it[16];
    unsigned pk[32];
    #pragma unroll
    for (int k = 0; k < 16; ++k) {
        int e = e0 + k * 256 + tid;
        bool v = (e < NUM_INTER);
        u[k]  = v ? iu[e] : -1;
        it[k] = v ? (NUM_USERS + ii[e]) : -1;
    }
    #pragma unroll
    for (int k = 0; k < 16; ++k) {
        if (u[k] >= 0) {
            int b0 = u[k] >> BSHIFT;
            int r0 = atomicAdd(&hist[b0], 1);
            pk[2 * k] = ((unsigned)b0 << 13) | (unsigned)r0;    // lrank < 8192
            int b1 = it[k] >> BSHIFT;
            int r1 = atomicAdd(&hist[b1], 1);
            pk[2 * k + 1] = ((unsigned)b1 << 13) | (unsigned)r1;
        }
    }
    __syncthreads();
    for (int b = tid; b < NBKT; b += 256) {
        int c = hist[b];
        if (c) gbase[b] = atomicAdd(&cursor[b * 16], c);
    }
    __syncthreads();
    #pragma unroll
    for (int k = 0; k < 16; ++k) {
        if (u[k] >= 0) {
            unsigned p0 = pk[2 * k];
            int b0 = (int)(p0 >> 13);
            int s0 = gbase[b0] + (int)(p0 & 0x1fffu);
            if (s0 < CAP)
                pairs[(size_t)b0 * CAP + s0] =
                    ((unsigned)(u[k] & (BNODES - 1)) << 19) | (unsigned)it[k];
            unsigned p1 = pk[2 * k + 1];
            int b1 = (int)(p1 >> 13);
            int s1 = gbase[b1] + (int)(p1 & 0x1fffu);
            if (s1 < CAP)
                pairs[(size_t)b1 * CAP + s1] =
                    ((unsigned)(it[k] & (BNODES - 1)) << 19) | (unsigned)u[k];
        }
    }
}

// ---------- pass B: everything bucket-local in ONE dispatch ----------
// per bucket block: count degrees (LDS) + flag neighbors-of-queried, local scan,
// write deg/factors/row_start (fixed region base b<<RSHIFT), scatter CSR,
// then convert this bucket's 512 emb rows to fp16 prescaled semb (dinv from LDS).
__global__ __launch_bounds__(256) void bucket_all_k(
        const int* __restrict__ cursor, const unsigned* __restrict__ pairs,
        const unsigned char* __restrict__ qflag, unsigned char* __restrict__ flag,
        int* __restrict__ deg, float* __restrict__ dinv, float* __restrict__ d2,
        float* __restrict__ rcp, int* __restrict__ row_start, int* __restrict__ nbr,
        const float* __restrict__ ue, const float* __restrict__ ie,
        _Float16* __restrict__ semb) {
    __shared__ int cnt[BNODES];
    __shared__ int lofs_s[BNODES];
    __shared__ float dinv_s[BNODES];
    __shared__ int sc[256];
    __shared__ unsigned qf[BNODES / 4];
    int b = blockIdx.x, tid = threadIdx.x;
    cnt[tid] = 0; cnt[tid + 256] = 0;
    if (tid < BNODES / 4)
        qf[tid] = ((const unsigned*)(qflag + ((size_t)b << BSHIFT)))[tid];
    __syncthreads();
    int n = cursor[b * 16]; if (n > CAP) n = CAP;
    const unsigned* p = pairs + (size_t)b * CAP;
    const unsigned char* qfb = (const unsigned char*)qf;
    for (int j = tid; j < n; j += 256) {
        unsigned code = p[j];
        int l = (int)(code >> 19);
        atomicAdd(&cnt[l], 1);
        if (qfb[l]) flag[code & PMASK] = 1;   // neighbor-of-queried
    }
    __syncthreads();

    int l0 = 2 * tid, l1 = l0 + 1;
    int c0 = cnt[l0], c1 = cnt[l1];
    int p0 = (c0 + 3) & ~3, p1 = (c1 + 3) & ~3;
    int s = p0 + p1;
    sc[tid] = s;
    __syncthreads();
    for (int o = 1; o < 256; o <<= 1) {
        int x = (tid >= o) ? sc[tid - o] : 0;
        __syncthreads();
        sc[tid] += x;
        __syncthreads();
    }
    int excl = sc[tid] - s;
    int gb = b << BSHIFT;
    int g0 = gb + l0, g1 = gb + l1;
    float fd0 = (float)c0, fd1 = (float)c1;
    float di0 = (c0 > 0) ? (1.0f / sqrtf(fd0)) : 0.0f;
    float di1 = (c1 > 0) ? (1.0f / sqrtf(fd1)) : 0.0f;
    if (g0 < N_NODES) {
        deg[g0] = c0; dinv[g0] = di0;
        d2[g0]  = (c0 > 0) ? (1.0f / fd0) : 0.0f;
        rcp[g0] = (c0 > 0) ? sqrtf(fd0) : 0.0f;
        row_start[g0] = (b << RSHIFT) + excl;
    }
    if (g1 < N_NODES) {
        deg[g1] = c1; dinv[g1] = di1;
        d2[g1]  = (c1 > 0) ? (1.0f / fd1) : 0.0f;
        rcp[g1] = (c1 > 0) ? sqrtf(fd1) : 0.0f;
        row_start[g1] = (b << RSHIFT) + excl + p0;
    }
    lofs_s[l0] = excl; lofs_s[l1] = excl + p0;
    dinv_s[l0] = di0;  dinv_s[l1] = di1;
    cnt[l0] = 0; cnt[l1] = 0;        // reuse as rank counters
    __syncthreads();

    int nbase = b << RSHIFT;
    for (int j = tid; j < n; j += 256) {
        unsigned code = p[j];
        int l = (int)(code >> 19);
        int r = atomicAdd(&cnt[l], 1);
        nbr[nbase + lofs_s[l] + r] = (int)(code & PMASK);
    }
    // conv for this bucket's nodes: semb[n] = dinv[n] * emb[n] (fp16, 128 B rows)
    for (int t = tid; t < BNODES * 8; t += 256) {
        int nl = t >> 3, q = t & 7;
        int node = gb + nl;
        if (node < N_NODES) {
            const float4* src = (node < NUM_USERS)
                ? (const float4*)ue + (size_t)node * 16
                : (const float4*)ie + (size_t)(node - NUM_USERS) * 16;
            float4 f0 = src[q * 2];
            float4 f1 = src[q * 2 + 1];
            float sdi = dinv_s[nl];
            half8 h;
            h[0] = (_Float16)(sdi * f0.x); h[1] = (_Float16)(sdi * f0.y);
            h[2] = (_Float16)(sdi * f0.z); h[3] = (_Float16)(sdi * f0.w);
            h[4] = (_Float16)(sdi * f1.x); h[5] = (_Float16)(sdi * f1.y);
            h[6] = (_Float16)(sdi * f1.z); h[7] = (_Float16)(sdi * f1.w);
            ((half8*)semb)[(size_t)node * 8 + q] = h;
        }
    }
}

// ---------- prop layer 1 (full, pure fp16 sum-gather): z1 = d2 * sum semb ----------
__global__ void prop_first_k(const int* __restrict__ row_start, const int* __restrict__ nbr,
                             const int* __restrict__ deg, const float* __restrict__ d2,
                             const _Float16* __restrict__ semb, _Float16* __restrict__ z1) {
    int t = blockIdx.x * blockDim.x + threadIdx.x;
    int node = t >> 3;
    int q = t & 7;
    if (node >= N_NODES) return;
    int d = deg[node];
    int beg = row_start[node];
    int lim = beg + d;
    int end = beg + ((d + 3) & ~3);
    const half8* src = (const half8*)semb;
    float a0 = 0.f, a1 = 0.f, a2 = 0.f, a3 = 0.f, a4 = 0.f, a5 = 0.f, a6 = 0.f, a7 = 0.f;
    for (int j = beg; j < end; j += 8) {
        vint4 na = __builtin_nontemporal_load((const vint4*)(nbr + j));
        vint4 nb = __builtin_nontemporal_load((const vint4*)(nbr + j + 4));
        #pragma unroll
        for (int k = 0; k < 8; ++k) {
            int id = (j + k < lim) ? ((k < 4) ? na[k] : nb[k - 4]) : N_NODES;
            half8 h = src[(size_t)id * 8 + q];
            a0 += (float)h[0]; a1 += (float)h[1]; a2 += (float)h[2]; a3 += (float)h[3];
            a4 += (float)h[4]; a5 += (float)h[5]; a6 += (float)h[6]; a7 += (float)h[7];
        }
    }
    float s = d2[node];
    half8 r;
    r[0] = (_Float16)(s * a0); r[1] = (_Float16)(s * a1);
    r[2] = (_Float16)(s * a2); r[3] = (_Float16)(s * a3);
    r[4] = (_Float16)(s * a4); r[5] = (_Float16)(s * a5);
    r[6] = (_Float16)(s * a6); r[7] = (_Float16)(s * a7);
    ((half8*)z1)[(size_t)node * 8 + q] = r;   // plain store: z1 is re-read (gathered) next pass
}

// ---------- prop layer 2 (node-ordered, flag-masked, fp16): z2 = d2 * sum z1 ----------
__global__ void prop_masked_k(const int* __restrict__ row_start, const int* __restrict__ nbr,
                              const int* __restrict__ deg, const float* __restrict__ d2,
                              const unsigned char* __restrict__ flag,
                              const _Float16* __restrict__ in, _Float16* __restrict__ out) {
    int t = blockIdx.x * blockDim.x + threadIdx.x;
    int node = t >> 3;
    int q = t & 7;
    if (node >= N_NODES) return;
    if (!flag[node]) return;   // z2 never read at unflagged nodes
    int d = deg[node];
    int beg = row_start[node];
    int lim = beg + d;
    int end = beg + ((d + 3) & ~3);
    const half8* src = (const half8*)in;
    float a0 = 0.f, a1 = 0.f, a2 = 0.f, a3 = 0.f, a4 = 0.f, a5 = 0.f, a6 = 0.f, a7 = 0.f;
    for (int j = beg; j < end; j += 8) {
        vint4 na = __builtin_nontemporal_load((const vint4*)(nbr + j));
        vint4 nb = __builtin_nontemporal_load((const vint4*)(nbr + j + 4));
        #pragma unroll
        for (int k = 0; k < 8; ++k) {
            int id = (j + k < lim) ? ((k < 4) ? na[k] : nb[k - 4]) : N_NODES;
            half8 h = src[(size_t)id * 8 + q];
            a0 += (float)h[0]; a1 += (float)h[1]; a2 += (float)h[2]; a3 += (float)h[3];
            a4 += (float)h[4]; a5 += (float)h[5]; a6 += (float)h[6]; a7 += (float)h[7];
        }
    }
    float s = d2[node];
    half8 r;
    r[0] = (_Float16)(s * a0); r[1] = (_Float16)(s * a1);
    r[2] = (_Float16)(s * a2); r[3] = (_Float16)(s * a3);
    r[4] = (_Float16)(s * a4); r[5] = (_Float16)(s * a5);
    r[6] = (_Float16)(s * a6); r[7] = (_Float16)(s * a7);
    ((half8*)out)[(size_t)node * 8 + q] = r;  // plain store: z2 re-read by score
}

// ---------- fused epilogue: layer-3 pull at queried nodes + layers 0-2 + dot ----------
// 16 lanes per (u,i) pair: 8 lanes user side, 8 lanes item side, 8 dims/lane
__global__ void fused_score_k(const int* __restrict__ row_start, const int* __restrict__ nbr,
                              const int* __restrict__ deg,
                              const float* __restrict__ dinv, const float* __restrict__ rcp,
                              const float* __restrict__ ue, const float* __restrict__ ie,
                              const _Float16* __restrict__ z1, const _Float16* __restrict__ z2,
                              const int* __restrict__ uid, const int* __restrict__ iid,
                              const float* __restrict__ w4, float* __restrict__ out) {
    int t = blockIdx.x * blockDim.x + threadIdx.x;
    int slot = t >> 4;
    if (slot >= BATCH) return;
    int within = t & 15;
    int side = within >> 3;
    int q = within & 7;

    int node;
    const float4* erow;
    if (side == 0) {
        int u = uid[slot];
        node = u;
        erow = (const float4*)ue + (size_t)u * 16;
    } else {
        int ii_ = iid[slot];
        node = NUM_USERS + ii_;
        erow = (const float4*)ie + (size_t)ii_ * 16;
    }

    float w0 = w4[0], w1 = w4[1], w2 = w4[2], w3 = w4[3];
    int d = deg[node];
    int beg = row_start[node];
    int lim = beg + d;
    int end = beg + ((d + 3) & ~3);
    const half8* z2v = (const half8*)z2;

    float a0 = 0.f, a1 = 0.f, a2 = 0.f, a3 = 0.f, a4 = 0.f, a5 = 0.f, a6 = 0.f, a7 = 0.f;
    for (int j = beg; j < end; j += 8) {
        vint4 na = __builtin_nontemporal_load((const vint4*)(nbr + j));
        vint4 nb = __builtin_nontemporal_load((const vint4*)(nbr + j + 4));
        #pragma unroll
        for (int k = 0; k < 8; ++k) {
            int id = (j + k < lim) ? ((k < 4) ? na[k] : nb[k - 4]) : N_NODES;
            half8 h = z2v[(size_t)id * 8 + q];
            a0 += (float)h[0]; a1 += (float)h[1]; a2 += (float)h[2]; a3 += (float)h[3];
            a4 += (float)h[4]; a5 += (float)h[5]; a6 += (float)h[6]; a7 += (float)h[7];
        }
    }

    float r  = rcp[node];
    float di = dinv[node];
    float e[8];
    *reinterpret_cast<float4*>(&e[0]) = erow[q * 2];
    *reinterpret_cast<float4*>(&e[4]) = erow[q * 2 + 1];
    half8 h1 = ((const half8*)z1)[(size_t)node * 8 + q];
    half8 h2 = z2v[(size_t)node * 8 + q];
    float acc[8] = {a0, a1, a2, a3, a4, a5, a6, a7};

    float f[8];
    #pragma unroll
    for (int dd = 0; dd < 8; ++dd)
        f[dd] = w0 * e[dd] + r * (w1 * (float)h1[dd] + w2 * (float)h2[dd]) + w3 * di * acc[dd];

    float pr = 0.f;
    #pragma unroll
    for (int dd = 0; dd < 8; ++dd) {
        float o = __shfl_xor(f[dd], 8);   // partner side, same dims
        pr += f[dd] * o;
    }
    pr += __shfl_xor(pr, 1);
    pr += __shfl_xor(pr, 2);
    pr += __shfl_xor(pr, 4);

    if (within == 0) out[slot] = pr;
}

// ---------- launch ----------

extern "C" void kernel_launch(void* const* d_in, const int* in_sizes, int n_in,
                              void* d_out, int out_size, void* d_ws, size_t ws_size,
                              hipStream_t stream) {
    const float* user_emb = (const float*)d_in[0];
    const float* item_emb = (const float*)d_in[1];
    const float* layer_w  = (const float*)d_in[2];
    const int*   inter_u  = (const int*)d_in[3];
    const int*   inter_i  = (const int*)d_in[4];
    const int*   user_ids = (const int*)d_in[5];
    const int*   item_ids = (const int*)d_in[6];
    float* out = (float*)d_out;

    char* base = (char*)d_ws;
    size_t off = 0;
    auto alloc = [&](size_t bytes) -> char* {
        char* p = base + off;
        off = (off + bytes + 255) & ~(size_t)255;
        return p;
    };
    float*    w4        = (float*)    alloc(4 * sizeof(float));
    int*      deg       = (int*)      alloc((size_t)N_NODES * sizeof(int));
    float*    dinv      = (float*)    alloc((size_t)N_NODES * sizeof(float));
    float*    d2        = (float*)    alloc((size_t)N_NODES * sizeof(float));
    float*    rcp       = (float*)    alloc((size_t)N_NODES * sizeof(float));
    int*      row_start = (int*)      alloc((size_t)N_NODES * sizeof(int));
    // zeroed region: flag + qflag + cursor (adjacent; single memset)
    unsigned char* flag   = (unsigned char*)alloc((size_t)N_NODES + 256);
    unsigned char* qflag  = (unsigned char*)alloc((size_t)N_NODES + 512);
    int*           cursor = (int*)          alloc((size_t)NBKT * 16 * sizeof(int));
    unsigned* pairs     = (unsigned*) alloc((size_t)NBKT * CAP * sizeof(unsigned));
    int*      csr_nbr   = (int*)      alloc((size_t)NBKT * RSLOTS * sizeof(int));
    _Float16* semb      = (_Float16*) alloc(((size_t)N_NODES + 1) * EMB * sizeof(_Float16));
    _Float16* zA        = (_Float16*) alloc(((size_t)N_NODES + 1) * EMB * sizeof(_Float16));
    _Float16* zB        = (_Float16*) alloc(((size_t)N_NODES + 1) * EMB * sizeof(_Float16));

    // 1. zero flag + qflag + bucket cursors (adjacent allocations, single memset)
    size_t span = (size_t)((char*)cursor - (char*)flag) + (size_t)NBKT * 16 * sizeof(int);
    hipMemsetAsync(flag, 0, span, stream);

    // 2. qmark (128 blk) + misc (softmax + dummy rows, 1 blk) + bucket scatter
    bucket_scatter_k<<<QMARK_BLOCKS + 1 + AB_BLOCKS, 256, 0, stream>>>(
        inter_u, inter_i, user_ids, item_ids, cursor, pairs, qflag, flag,
        layer_w, w4, semb, zB, zA);

    // 3. bucket-local: degrees + factors + row_start + CSR scatter + fp16 conv
    bucket_all_k<<<NBKT, 256, 0, stream>>>(
        cursor, pairs, qflag, flag, deg, dinv, d2, rcp, row_start, csr_nbr,
        user_emb, item_emb, semb);

    // 4. layer 1 full (pure fp16 sum-gather): zB = z1
    prop_first_k<<<PROP_BLOCKS, 256, 0, stream>>>(
        row_start, csr_nbr, deg, d2, semb, zB);

    // 5. layer 2 flag-masked, node-ordered, fp16: zA = z2
    prop_masked_k<<<PROP_BLOCKS, 256, 0, stream>>>(
        row_start, csr_nbr, deg, d2, flag, zB, zA);

    // 6. fused: layer-3 pull at queried nodes + layer 0-2 terms + dot product
    fused_score_k<<<(BATCH * 16 + 255) / 256, 256, 0, stream>>>(
        row_start, csr_nbr, deg, dinv, rcp, user_emb, item_emb,
        zB /*z1*/, zA /*z2*/, user_ids, item_ids, w4, out);
}

// Round 6
// 260.013 us; speedup vs baseline: 3.2361x; 1.0287x over previous
//
#include <hip/hip_runtime.h>
#include <math.h>

#define NUM_USERS 100000
#define NUM_ITEMS 200000
#define N_NODES   300000   // NUM_USERS + NUM_ITEMS
#define EMB       64
#define NUM_INTER 1000000
#define BATCH     16384

// ---- bucketed CSR builder geometry ----
#define BSHIFT 9
#define BNODES 512
#define NBKT   ((N_NODES + BNODES - 1) / BNODES)    // 586
#define CAP    6144       // refs per bucket (max expected ~5400)
#define RSHIFT 13         // fixed nbr region per bucket: 8192 slots (max padded use 7680)
#define RSLOTS (1 << RSHIFT)
#define EDGES_PER_BLOCK 4096                        // 8192 refs per scatter block
#define AB_BLOCKS ((NUM_INTER + EDGES_PER_BLOCK - 1) / EDGES_PER_BLOCK)   // 245
#define QMARK_BLOCKS ((BATCH * 2) / 256)            // 128
#define CONV_BLOCKS ((N_NODES * 8 + 255) / 256)     // 9375
#define CONV_BASE   (QMARK_BLOCKS + 1 + AB_BLOCKS)  // 374

#define PROP_BLOCKS ((N_NODES * 8 + 255) / 256)  // 9375

typedef int      vint4 __attribute__((ext_vector_type(4)));
typedef _Float16 half8 __attribute__((ext_vector_type(8)));

// pair code: (local_node_in_bucket << 19) | partner   (local<512, partner<2^19)
#define PMASK 0x7FFFFu

// ---------- pass A: qmark + misc + scatter + fp16 emb cast (dinv-free!) ----------
// conv has NO dependency on degrees because prop1 applies dinv at gather time,
// so the 115 MB of conv streaming rides in this dispatch's spare occupancy.
__global__ __launch_bounds__(256) void bucket_scatter_k(
        const int* __restrict__ iu, const int* __restrict__ ii,
        const int* __restrict__ uid, const int* __restrict__ iid,
        int* __restrict__ cursor /*stride 16 ints*/, unsigned* __restrict__ pairs,
        unsigned char* __restrict__ qflag, unsigned char* __restrict__ flag,
        const float* __restrict__ lw, float* __restrict__ w4,
        float* __restrict__ dinv,
        const float* __restrict__ ue, const float* __restrict__ ie,
        _Float16* __restrict__ semb, _Float16* __restrict__ z1, _Float16* __restrict__ z2) {
    int tid = threadIdx.x;
    if (blockIdx.x < QMARK_BLOCKS) {
        int t = blockIdx.x * 256 + tid;               // < BATCH*2 exactly
        int node = (t & 1) ? (NUM_USERS + iid[t >> 1]) : uid[t >> 1];
        qflag[node] = 1;
        flag[node]  = 1;                              // queried nodes need z2 too
        return;
    }
    if (blockIdx.x == QMARK_BLOCKS) {
        // misc: zero dummy row (idx N_NODES, 128 B) of each fp16 table + softmax(lw)
        if (tid < 96) {
            unsigned* p = (tid < 32) ? (unsigned*)semb : (tid < 64) ? (unsigned*)z1 : (unsigned*)z2;
            p[(size_t)N_NODES * 32 + (tid & 31)] = 0u;
        }
        if (tid == 96) dinv[N_NODES] = 0.0f;          // padding lanes gather dinv[N_NODES]
        if (tid == 0) {
            float a = lw[0], b = lw[1], c = lw[2], d = lw[3];
            float m = fmaxf(fmaxf(a, b), fmaxf(c, d));
            float e0 = expf(a - m), e1 = expf(b - m), e2 = expf(c - m), e3 = expf(d - m);
            float sm = e0 + e1 + e2 + e3;
            w4[0] = e0 / sm; w4[1] = e1 / sm; w4[2] = e2 / sm; w4[3] = e3 / sm;
        }
        return;
    }
    if (blockIdx.x >= CONV_BASE) {
        // conv: semb[n] = (fp16) emb[n]  (plain cast, 128 B rows)
        int t = (blockIdx.x - CONV_BASE) * 256 + tid;
        int node = t >> 3;
        int q = t & 7;
        if (node >= N_NODES) return;
        const float4* src = (node < NUM_USERS)
            ? (const float4*)ue + (size_t)node * 16
            : (const float4*)ie + (size_t)(node - NUM_USERS) * 16;
        float4 f0 = src[q * 2];
        float4 f1 = src[q * 2 + 1];
        half8 h;
        h[0] = (_Float16)f0.x; h[1] = (_Float16)f0.y;
        h[2] = (_Float16)f0.z; h[3] = (_Float16)f0.w;
        h[4] = (_Float16)f1.x; h[5] = (_Float16)f1.y;
        h[6] = (_Float16)f1.z; h[7] = (_Float16)f1.w;
        ((half8*)semb)[(size_t)node * 8 + q] = h;
        return;
    }
    __shared__ int hist[NBKT];
    __shared__ int gbase[NBKT];
    int bid = blockIdx.x - QMARK_BLOCKS - 1;
    for (int b = tid; b < NBKT; b += 256) hist[b] = 0;
    __syncthreads();

    int e0 = bid * EDGES_PER_BLOCK;
    int u[16], it[16];
    unsigned pk[32];
    #pragma unroll
    for (int k = 0; k < 16; ++k) {
        int e = e0 + k * 256 + tid;
        bool v = (e < NUM_INTER);
        u[k]  = v ? iu[e] : -1;
        it[k] = v ? (NUM_USERS + ii[e]) : -1;
    }
    #pragma unroll
    for (int k = 0; k < 16; ++k) {
        if (u[k] >= 0) {
            int b0 = u[k] >> BSHIFT;
            int r0 = atomicAdd(&hist[b0], 1);
            pk[2 * k] = ((unsigned)b0 << 13) | (unsigned)r0;    // lrank < 8192
            int b1 = it[k] >> BSHIFT;
            int r1 = atomicAdd(&hist[b1], 1);
            pk[2 * k + 1] = ((unsigned)b1 << 13) | (unsigned)r1;
        }
    }
    __syncthreads();
    for (int b = tid; b < NBKT; b += 256) {
        int c = hist[b];
        if (c) gbase[b] = atomicAdd(&cursor[b * 16], c);
    }
    __syncthreads();
    #pragma unroll
    for (int k = 0; k < 16; ++k) {
        if (u[k] >= 0) {
            unsigned p0 = pk[2 * k];
            int b0 = (int)(p0 >> 13);
            int s0 = gbase[b0] + (int)(p0 & 0x1fffu);
            if (s0 < CAP)
                pairs[(size_t)b0 * CAP + s0] =
                    ((unsigned)(u[k] & (BNODES - 1)) << 19) | (unsigned)it[k];
            unsigned p1 = pk[2 * k + 1];
            int b1 = (int)(p1 >> 13);
            int s1 = gbase[b1] + (int)(p1 & 0x1fffu);
            if (s1 < CAP)
                pairs[(size_t)b1 * CAP + s1] =
                    ((unsigned)(it[k] & (BNODES - 1)) << 19) | (unsigned)u[k];
        }
    }
}

// ---------- pass B: bucket-local CSR (no conv): degrees + factors + row_start + scatter ----------
__global__ __launch_bounds__(256) void bucket_all_k(
        const int* __restrict__ cursor, const unsigned* __restrict__ pairs,
        const unsigned char* __restrict__ qflag, unsigned char* __restrict__ flag,
        int* __restrict__ deg, float* __restrict__ dinv, float* __restrict__ d2,
        float* __restrict__ rcp, int* __restrict__ row_start, int* __restrict__ nbr) {
    __shared__ int cnt[BNODES];
    __shared__ int lofs_s[BNODES];
    __shared__ int sc[256];
    __shared__ unsigned qf[BNODES / 4];
    int b = blockIdx.x, tid = threadIdx.x;
    cnt[tid] = 0; cnt[tid + 256] = 0;
    if (tid < BNODES / 4)
        qf[tid] = ((const unsigned*)(qflag + ((size_t)b << BSHIFT)))[tid];
    __syncthreads();
    int n = cursor[b * 16]; if (n > CAP) n = CAP;
    const unsigned* p = pairs + (size_t)b * CAP;
    const unsigned char* qfb = (const unsigned char*)qf;
    for (int j = tid; j < n; j += 256) {
        unsigned code = p[j];
        int l = (int)(code >> 19);
        atomicAdd(&cnt[l], 1);
        if (qfb[l]) flag[code & PMASK] = 1;   // neighbor-of-queried
    }
    __syncthreads();

    int l0 = 2 * tid, l1 = l0 + 1;
    int c0 = cnt[l0], c1 = cnt[l1];
    int p0 = (c0 + 3) & ~3, p1 = (c1 + 3) & ~3;
    int s = p0 + p1;
    sc[tid] = s;
    __syncthreads();
    for (int o = 1; o < 256; o <<= 1) {
        int x = (tid >= o) ? sc[tid - o] : 0;
        __syncthreads();
        sc[tid] += x;
        __syncthreads();
    }
    int excl = sc[tid] - s;
    int gb = b << BSHIFT;
    int g0 = gb + l0, g1 = gb + l1;
    float fd0 = (float)c0, fd1 = (float)c1;
    if (g0 < N_NODES) {
        deg[g0] = c0;
        dinv[g0] = (c0 > 0) ? (1.0f / sqrtf(fd0)) : 0.0f;
        d2[g0]  = (c0 > 0) ? (1.0f / fd0) : 0.0f;
        rcp[g0] = (c0 > 0) ? sqrtf(fd0) : 0.0f;
        row_start[g0] = (b << RSHIFT) + excl;
    }
    if (g1 < N_NODES) {
        deg[g1] = c1;
        dinv[g1] = (c1 > 0) ? (1.0f / sqrtf(fd1)) : 0.0f;
        d2[g1]  = (c1 > 0) ? (1.0f / fd1) : 0.0f;
        rcp[g1] = (c1 > 0) ? sqrtf(fd1) : 0.0f;
        row_start[g1] = (b << RSHIFT) + excl + p0;
    }
    lofs_s[l0] = excl; lofs_s[l1] = excl + p0;
    cnt[l0] = 0; cnt[l1] = 0;        // reuse as rank counters
    __syncthreads();

    int nbase = b << RSHIFT;
    for (int j = tid; j < n; j += 256) {
        unsigned code = p[j];
        int l = (int)(code >> 19);
        int r = atomicAdd(&cnt[l], 1);
        nbr[nbase + lofs_s[l] + r] = (int)(code & PMASK);
    }
}

// ---------- prop layer 1 (full): z1[v] = d2[v] * sum dinv[n] * semb16[n] ----------
__global__ void prop_first_k(const int* __restrict__ row_start, const int* __restrict__ nbr,
                             const int* __restrict__ deg, const float* __restrict__ d2,
                             const float* __restrict__ dinv,
                             const _Float16* __restrict__ semb, _Float16* __restrict__ z1) {
    int t = blockIdx.x * blockDim.x + threadIdx.x;
    int node = t >> 3;
    int q = t & 7;
    if (node >= N_NODES) return;
    int d = deg[node];
    int beg = row_start[node];
    int lim = beg + d;
    int end = beg + ((d + 3) & ~3);
    const half8* src = (const half8*)semb;
    float a0 = 0.f, a1 = 0.f, a2 = 0.f, a3 = 0.f, a4 = 0.f, a5 = 0.f, a6 = 0.f, a7 = 0.f;
    for (int j = beg; j < end; j += 8) {
        vint4 na = __builtin_nontemporal_load((const vint4*)(nbr + j));
        vint4 nb = __builtin_nontemporal_load((const vint4*)(nbr + j + 4));
        #pragma unroll
        for (int k = 0; k < 8; ++k) {
            int id = (j + k < lim) ? ((k < 4) ? na[k] : nb[k - 4]) : N_NODES;
            float w = dinv[id];                  // dinv[N_NODES] == 0 (misc block)
            half8 h = src[(size_t)id * 8 + q];
            a0 += w * (float)h[0]; a1 += w * (float)h[1];
            a2 += w * (float)h[2]; a3 += w * (float)h[3];
            a4 += w * (float)h[4]; a5 += w * (float)h[5];
            a6 += w * (float)h[6]; a7 += w * (float)h[7];
        }
    }
    float s = d2[node];
    half8 r;
    r[0] = (_Float16)(s * a0); r[1] = (_Float16)(s * a1);
    r[2] = (_Float16)(s * a2); r[3] = (_Float16)(s * a3);
    r[4] = (_Float16)(s * a4); r[5] = (_Float16)(s * a5);
    r[6] = (_Float16)(s * a6); r[7] = (_Float16)(s * a7);
    ((half8*)z1)[(size_t)node * 8 + q] = r;   // plain store: z1 re-read (gathered) next pass
}

// ---------- prop layer 2 (node-ordered, flag-masked, fp16): z2 = d2 * sum z1 ----------
__global__ void prop_masked_k(const int* __restrict__ row_start, const int* __restrict__ nbr,
                              const int* __restrict__ deg, const float* __restrict__ d2,
                              const unsigned char* __restrict__ flag,
                              const _Float16* __restrict__ in, _Float16* __restrict__ out) {
    int t = blockIdx.x * blockDim.x + threadIdx.x;
    int node = t >> 3;
    int q = t & 7;
    if (node >= N_NODES) return;
    if (!flag[node]) return;   // z2 never read at unflagged nodes
    int d = deg[node];
    int beg = row_start[node];
    int lim = beg + d;
    int end = beg + ((d + 3) & ~3);
    const half8* src = (const half8*)in;
    float a0 = 0.f, a1 = 0.f, a2 = 0.f, a3 = 0.f, a4 = 0.f, a5 = 0.f, a6 = 0.f, a7 = 0.f;
    for (int j = beg; j < end; j += 8) {
        vint4 na = __builtin_nontemporal_load((const vint4*)(nbr + j));
        vint4 nb = __builtin_nontemporal_load((const vint4*)(nbr + j + 4));
        #pragma unroll
        for (int k = 0; k < 8; ++k) {
            int id = (j + k < lim) ? ((k < 4) ? na[k] : nb[k - 4]) : N_NODES;
            half8 h = src[(size_t)id * 8 + q];
            a0 += (float)h[0]; a1 += (float)h[1]; a2 += (float)h[2]; a3 += (float)h[3];
            a4 += (float)h[4]; a5 += (float)h[5]; a6 += (float)h[6]; a7 += (float)h[7];
        }
    }
    float s = d2[node];
    half8 r;
    r[0] = (_Float16)(s * a0); r[1] = (_Float16)(s * a1);
    r[2] = (_Float16)(s * a2); r[3] = (_Float16)(s * a3);
    r[4] = (_Float16)(s * a4); r[5] = (_Float16)(s * a5);
    r[6] = (_Float16)(s * a6); r[7] = (_Float16)(s * a7);
    ((half8*)out)[(size_t)node * 8 + q] = r;  // plain store: z2 re-read by score
}

// ---------- fused epilogue: layer-3 pull at queried nodes + layers 0-2 + dot ----------
// 16 lanes per (u,i) pair: 8 lanes user side, 8 lanes item side, 8 dims/lane
__global__ void fused_score_k(const int* __restrict__ row_start, const int* __restrict__ nbr,
                              const int* __restrict__ deg,
                              const float* __restrict__ dinv, const float* __restrict__ rcp,
                              const float* __restrict__ ue, const float* __restrict__ ie,
                              const _Float16* __restrict__ z1, const _Float16* __restrict__ z2,
                              const int* __restrict__ uid, const int* __restrict__ iid,
                              const float* __restrict__ w4, float* __restrict__ out) {
    int t = blockIdx.x * blockDim.x + threadIdx.x;
    int slot = t >> 4;
    if (slot >= BATCH) return;
    int within = t & 15;
    int side = within >> 3;
    int q = within & 7;

    int node;
    const float4* erow;
    if (side == 0) {
        int u = uid[slot];
        node = u;
        erow = (const float4*)ue + (size_t)u * 16;
    } else {
        int ii_ = iid[slot];
        node = NUM_USERS + ii_;
        erow = (const float4*)ie + (size_t)ii_ * 16;
    }

    float w0 = w4[0], w1 = w4[1], w2 = w4[2], w3 = w4[3];
    int d = deg[node];
    int beg = row_start[node];
    int lim = beg + d;
    int end = beg + ((d + 3) & ~3);
    const half8* z2v = (const half8*)z2;

    float a0 = 0.f, a1 = 0.f, a2 = 0.f, a3 = 0.f, a4 = 0.f, a5 = 0.f, a6 = 0.f, a7 = 0.f;
    for (int j = beg; j < end; j += 8) {
        vint4 na = __builtin_nontemporal_load((const vint4*)(nbr + j));
        vint4 nb = __builtin_nontemporal_load((const vint4*)(nbr + j + 4));
        #pragma unroll
        for (int k = 0; k < 8; ++k) {
            int id = (j + k < lim) ? ((k < 4) ? na[k] : nb[k - 4]) : N_NODES;
            half8 h = z2v[(size_t)id * 8 + q];
            a0 += (float)h[0]; a1 += (float)h[1]; a2 += (float)h[2]; a3 += (float)h[3];
            a4 += (float)h[4]; a5 += (float)h[5]; a6 += (float)h[6]; a7 += (float)h[7];
        }
    }

    float r  = rcp[node];
    float di = dinv[node];
    float e[8];
    *reinterpret_cast<float4*>(&e[0]) = erow[q * 2];
    *reinterpret_cast<float4*>(&e[4]) = erow[q * 2 + 1];
    half8 h1 = ((const half8*)z1)[(size_t)node * 8 + q];
    half8 h2 = z2v[(size_t)node * 8 + q];
    float acc[8] = {a0, a1, a2, a3, a4, a5, a6, a7};

    float f[8];
    #pragma unroll
    for (int dd = 0; dd < 8; ++dd)
        f[dd] = w0 * e[dd] + r * (w1 * (float)h1[dd] + w2 * (float)h2[dd]) + w3 * di * acc[dd];

    float pr = 0.f;
    #pragma unroll
    for (int dd = 0; dd < 8; ++dd) {
        float o = __shfl_xor(f[dd], 8);   // partner side, same dims
        pr += f[dd] * o;
    }
    pr += __shfl_xor(pr, 1);
    pr += __shfl_xor(pr, 2);
    pr += __shfl_xor(pr, 4);

    if (within == 0) out[slot] = pr;
}

// ---------- launch ----------

extern "C" void kernel_launch(void* const* d_in, const int* in_sizes, int n_in,
                              void* d_out, int out_size, void* d_ws, size_t ws_size,
                              hipStream_t stream) {
    const float* user_emb = (const float*)d_in[0];
    const float* item_emb = (const float*)d_in[1];
    const float* layer_w  = (const float*)d_in[2];
    const int*   inter_u  = (const int*)d_in[3];
    const int*   inter_i  = (const int*)d_in[4];
    const int*   user_ids = (const int*)d_in[5];
    const int*   item_ids = (const int*)d_in[6];
    float* out = (float*)d_out;

    char* base = (char*)d_ws;
    size_t off = 0;
    auto alloc = [&](size_t bytes) -> char* {
        char* p = base + off;
        off = (off + bytes + 255) & ~(size_t)255;
        return p;
    };
    float*    w4        = (float*)    alloc(4 * sizeof(float));
    int*      deg       = (int*)      alloc((size_t)N_NODES * sizeof(int));
    float*    dinv      = (float*)    alloc(((size_t)N_NODES + 1) * sizeof(float));  // +1: padding slot
    float*    d2        = (float*)    alloc((size_t)N_NODES * sizeof(float));
    float*    rcp       = (float*)    alloc((size_t)N_NODES * sizeof(float));
    int*      row_start = (int*)      alloc((size_t)N_NODES * sizeof(int));
    // zeroed region: flag + qflag + cursor (adjacent; single memset)
    unsigned char* flag   = (unsigned char*)alloc((size_t)N_NODES + 256);
    unsigned char* qflag  = (unsigned char*)alloc((size_t)N_NODES + 512);
    int*           cursor = (int*)          alloc((size_t)NBKT * 16 * sizeof(int));
    unsigned* pairs     = (unsigned*) alloc((size_t)NBKT * CAP * sizeof(unsigned));
    int*      csr_nbr   = (int*)      alloc((size_t)NBKT * RSLOTS * sizeof(int));
    _Float16* semb      = (_Float16*) alloc(((size_t)N_NODES + 1) * EMB * sizeof(_Float16));
    _Float16* zA        = (_Float16*) alloc(((size_t)N_NODES + 1) * EMB * sizeof(_Float16));
    _Float16* zB        = (_Float16*) alloc(((size_t)N_NODES + 1) * EMB * sizeof(_Float16));

    // 1. zero flag + qflag + bucket cursors (adjacent allocations, single memset)
    size_t span = (size_t)((char*)cursor - (char*)flag) + (size_t)NBKT * 16 * sizeof(int);
    hipMemsetAsync(flag, 0, span, stream);

    // 2. qmark + misc + bucket scatter + fp16 emb cast (dependency-free conv rides here)
    bucket_scatter_k<<<QMARK_BLOCKS + 1 + AB_BLOCKS + CONV_BLOCKS, 256, 0, stream>>>(
        inter_u, inter_i, user_ids, item_ids, cursor, pairs, qflag, flag,
        layer_w, w4, dinv, user_emb, item_emb, semb, zB, zA);

    // 3. bucket-local: degrees + factors + row_start + CSR scatter (no conv tail)
    bucket_all_k<<<NBKT, 256, 0, stream>>>(
        cursor, pairs, qflag, flag, deg, dinv, d2, rcp, row_start, csr_nbr);

    // 4. layer 1 full (fp16 sum-gather, dinv applied at gather): zB = z1
    prop_first_k<<<PROP_BLOCKS, 256, 0, stream>>>(
        row_start, csr_nbr, deg, d2, dinv, semb, zB);

    // 5. layer 2 flag-masked, node-ordered, fp16: zA = z2
    prop_masked_k<<<PROP_BLOCKS, 256, 0, stream>>>(
        row_start, csr_nbr, deg, d2, flag, zB, zA);

    // 6. fused: layer-3 pull at queried nodes + layer 0-2 terms + dot product
    fused_score_k<<<(BATCH * 16 + 255) / 256, 256, 0, stream>>>(
        row_start, csr_nbr, deg, dinv, rcp, user_emb, item_emb,
        zB /*z1*/, zA /*z2*/, user_ids, item_ids, w4, out);
}

// Round 7
// 252.770 us; speedup vs baseline: 3.3288x; 1.0287x over previous
//
#include <hip/hip_runtime.h>
#include <hip/hip_fp8.h>
#include <math.h>

#define NUM_USERS 100000
#define NUM_ITEMS 200000
#define N_NODES   300000   // NUM_USERS + NUM_ITEMS
#define EMB       64
#define NUM_INTER 1000000
#define BATCH     16384

// ---- bucketed CSR builder geometry ----
#define BSHIFT 9
#define BNODES 512
#define NBKT   ((N_NODES + BNODES - 1) / BNODES)    // 586
#define CAP    6144       // refs per bucket (max expected ~5400)
#define RSHIFT 13         // fixed nbr region per bucket: 8192 slots (max padded use 7680)
#define RSLOTS (1 << RSHIFT)
#define EDGES_PER_BLOCK 4096                        // 8192 refs per scatter block
#define AB_BLOCKS ((NUM_INTER + EDGES_PER_BLOCK - 1) / EDGES_PER_BLOCK)   // 245
#define QMARK_BLOCKS ((BATCH * 2) / 256)            // 128
#define CONV_BLOCKS ((N_NODES * 8 + 255) / 256)     // 9375
#define CONV_BASE   (QMARK_BLOCKS + 1 + AB_BLOCKS)  // 374

#define PROP_BLOCKS ((N_NODES * 8 + 255) / 256)  // 9375

typedef int      vint4 __attribute__((ext_vector_type(4)));
typedef _Float16 half8 __attribute__((ext_vector_type(8)));

// pair code: (local_node_in_bucket << 19) | partner   (local<512, partner<2^19)
#define PMASK 0x7FFFFu

// fp8 e4m3 helpers: semb stores fp8(emb * 256); 2^-8 folded into z1 scale.
// (emb values ~5e-3 are SUBNORMAL in e4m3; x256 puts them in the normal range)
#define FP8_SCALE   256.0f
#define FP8_INVSCALE (1.0f / 256.0f)

__device__ __forceinline__ float fp8d(unsigned v) {   // decode low byte
    __hip_fp8_e4m3 h;
    __builtin_memcpy(&h, &v, 1);
    return (float)h;
}
__device__ __forceinline__ unsigned fp8e(float f) {   // encode to byte
    __hip_fp8_e4m3 h(f);
    unsigned char b;
    __builtin_memcpy(&b, &h, 1);
    return (unsigned)b;
}

// ---------- pass A: qmark + misc + scatter + fp8 emb cast (dinv-free) ----------
__global__ __launch_bounds__(256) void bucket_scatter_k(
        const int* __restrict__ iu, const int* __restrict__ ii,
        const int* __restrict__ uid, const int* __restrict__ iid,
        int* __restrict__ cursor /*stride 16 ints*/, unsigned* __restrict__ pairs,
        unsigned char* __restrict__ qflag, unsigned char* __restrict__ flag,
        const float* __restrict__ lw, float* __restrict__ w4,
        float* __restrict__ dinv,
        const float* __restrict__ ue, const float* __restrict__ ie,
        unsigned char* __restrict__ semb, _Float16* __restrict__ z1,
        _Float16* __restrict__ z2) {
    int tid = threadIdx.x;
    if (blockIdx.x < QMARK_BLOCKS) {
        int t = blockIdx.x * 256 + tid;               // < BATCH*2 exactly
        int node = (t & 1) ? (NUM_USERS + iid[t >> 1]) : uid[t >> 1];
        qflag[node] = 1;
        flag[node]  = 1;                              // queried nodes need z2 too
        return;
    }
    if (blockIdx.x == QMARK_BLOCKS) {
        // misc: zero dummy rows (semb 64 B, z1/z2 128 B) + padding dinv + softmax
        if (tid < 16)  ((unsigned*)semb)[(size_t)N_NODES * 16 + tid] = 0u;
        if (tid >= 32 && tid < 64) ((unsigned*)z1)[(size_t)N_NODES * 32 + (tid - 32)] = 0u;
        if (tid >= 64 && tid < 96) ((unsigned*)z2)[(size_t)N_NODES * 32 + (tid - 64)] = 0u;
        if (tid == 96) dinv[N_NODES] = 0.0f;          // padding lanes gather dinv[N_NODES]
        if (tid == 0) {
            float a = lw[0], b = lw[1], c = lw[2], d = lw[3];
            float m = fmaxf(fmaxf(a, b), fmaxf(c, d));
            float e0 = expf(a - m), e1 = expf(b - m), e2 = expf(c - m), e3 = expf(d - m);
            float sm = e0 + e1 + e2 + e3;
            w4[0] = e0 / sm; w4[1] = e1 / sm; w4[2] = e2 / sm; w4[3] = e3 / sm;
        }
        return;
    }
    if (blockIdx.x >= CONV_BASE) {
        // conv: semb[n] = fp8(emb[n] * 256)   (64 B rows, no degree dependency)
        int t = (blockIdx.x - CONV_BASE) * 256 + tid;
        int node = t >> 3;
        int q = t & 7;
        if (node >= N_NODES) return;
        const float4* src = (node < NUM_USERS)
            ? (const float4*)ue + (size_t)node * 16
            : (const float4*)ie + (size_t)(node - NUM_USERS) * 16;
        float4 f0 = src[q * 2];
        float4 f1 = src[q * 2 + 1];
        unsigned b0 = fp8e(f0.x * FP8_SCALE)        | (fp8e(f0.y * FP8_SCALE) << 8)
                    | (fp8e(f0.z * FP8_SCALE) << 16)| (fp8e(f0.w * FP8_SCALE) << 24);
        unsigned b1 = fp8e(f1.x * FP8_SCALE)        | (fp8e(f1.y * FP8_SCALE) << 8)
                    | (fp8e(f1.z * FP8_SCALE) << 16)| (fp8e(f1.w * FP8_SCALE) << 24);
        ((uint2*)semb)[(size_t)node * 8 + q] = make_uint2(b0, b1);
        return;
    }
    __shared__ int hist[NBKT];
    __shared__ int gbase[NBKT];
    int bid = blockIdx.x - QMARK_BLOCKS - 1;
    for (int b = tid; b < NBKT; b += 256) hist[b] = 0;
    __syncthreads();

    int e0 = bid * EDGES_PER_BLOCK;
    int u[16], it[16];
    unsigned pk[32];
    #pragma unroll
    for (int k = 0; k < 16; ++k) {
        int e = e0 + k * 256 + tid;
        bool v = (e < NUM_INTER);
        u[k]  = v ? iu[e] : -1;
        it[k] = v ? (NUM_USERS + ii[e]) : -1;
    }
    #pragma unroll
    for (int k = 0; k < 16; ++k) {
        if (u[k] >= 0) {
            int b0 = u[k] >> BSHIFT;
            int r0 = atomicAdd(&hist[b0], 1);
            pk[2 * k] = ((unsigned)b0 << 13) | (unsigned)r0;    // lrank < 8192
            int b1 = it[k] >> BSHIFT;
            int r1 = atomicAdd(&hist[b1], 1);
            pk[2 * k + 1] = ((unsigned)b1 << 13) | (unsigned)r1;
        }
    }
    __syncthreads();
    for (int b = tid; b < NBKT; b += 256) {
        int c = hist[b];
        if (c) gbase[b] = atomicAdd(&cursor[b * 16], c);
    }
    __syncthreads();
    #pragma unroll
    for (int k = 0; k < 16; ++k) {
        if (u[k] >= 0) {
            unsigned p0 = pk[2 * k];
            int b0 = (int)(p0 >> 13);
            int s0 = gbase[b0] + (int)(p0 & 0x1fffu);
            if (s0 < CAP)
                pairs[(size_t)b0 * CAP + s0] =
                    ((unsigned)(u[k] & (BNODES - 1)) << 19) | (unsigned)it[k];
            unsigned p1 = pk[2 * k + 1];
            int b1 = (int)(p1 >> 13);
            int s1 = gbase[b1] + (int)(p1 & 0x1fffu);
            if (s1 < CAP)
                pairs[(size_t)b1 * CAP + s1] =
                    ((unsigned)(it[k] & (BNODES - 1)) << 19) | (unsigned)u[k];
        }
    }
}

// ---------- pass B: bucket-local CSR, 1024 threads (scan 512-wide, 4x stream width) ----------
__global__ __launch_bounds__(1024) void bucket_all_k(
        const int* __restrict__ cursor, const unsigned* __restrict__ pairs,
        const unsigned char* __restrict__ qflag, unsigned char* __restrict__ flag,
        int* __restrict__ deg, float* __restrict__ dinv, float* __restrict__ d2,
        float* __restrict__ rcp, int* __restrict__ row_start, int* __restrict__ nbr) {
    __shared__ int cnt[BNODES];
    __shared__ int lofs_s[BNODES];
    __shared__ int sc[BNODES];
    __shared__ unsigned qf[BNODES / 4];
    int b = blockIdx.x, tid = threadIdx.x;
    if (tid < BNODES) cnt[tid] = 0;
    if (tid < BNODES / 4)
        qf[tid] = ((const unsigned*)(qflag + ((size_t)b << BSHIFT)))[tid];
    __syncthreads();
    int n = cursor[b * 16]; if (n > CAP) n = CAP;
    const unsigned* p = pairs + (size_t)b * CAP;
    const unsigned char* qfb = (const unsigned char*)qf;
    for (int j = tid; j < n; j += 1024) {
        unsigned code = p[j];
        int l = (int)(code >> 19);
        atomicAdd(&cnt[l], 1);
        if (qfb[l]) flag[code & PMASK] = 1;   // neighbor-of-queried
    }
    __syncthreads();

    int c = 0, pd = 0;
    if (tid < BNODES) { c = cnt[tid]; pd = (c + 3) & ~3; sc[tid] = pd; }
    __syncthreads();
    for (int o = 1; o < BNODES; o <<= 1) {
        int x = (tid >= o && tid < BNODES) ? sc[tid - o] : 0;
        __syncthreads();
        if (tid < BNODES) sc[tid] += x;
        __syncthreads();
    }
    if (tid < BNODES) {
        int excl = sc[tid] - pd;
        int g = (b << BSHIFT) + tid;
        if (g < N_NODES) {
            deg[g] = c;
            float fd = (float)c;
            dinv[g] = (c > 0) ? (1.0f / sqrtf(fd)) : 0.0f;
            d2[g]   = (c > 0) ? (1.0f / fd) : 0.0f;
            rcp[g]  = (c > 0) ? sqrtf(fd) : 0.0f;
            row_start[g] = (b << RSHIFT) + excl;
        }
        lofs_s[tid] = excl;
        cnt[tid] = 0;                 // reuse as rank counters
    }
    __syncthreads();

    int nbase = b << RSHIFT;
    for (int j = tid; j < n; j += 1024) {
        unsigned code = p[j];
        int l = (int)(code >> 19);
        int r = atomicAdd(&cnt[l], 1);
        nbr[nbase + lofs_s[l] + r] = (int)(code & PMASK);
    }
}

// ---------- prop layer 1: z1[v] = d2[v]/256 * sum dinv[n] * fp8semb[n] ----------
__global__ void prop_first_k(const int* __restrict__ row_start, const int* __restrict__ nbr,
                             const int* __restrict__ deg, const float* __restrict__ d2,
                             const float* __restrict__ dinv,
                             const unsigned char* __restrict__ semb, _Float16* __restrict__ z1) {
    int t = blockIdx.x * blockDim.x + threadIdx.x;
    int node = t >> 3;
    int q = t & 7;
    if (node >= N_NODES) return;
    int d = deg[node];
    int beg = row_start[node];
    int lim = beg + d;
    int end = beg + ((d + 3) & ~3);
    const uint2* src = (const uint2*)semb;    // 64 B rows: 8 threads x 8 B
    float a0 = 0.f, a1 = 0.f, a2 = 0.f, a3 = 0.f, a4 = 0.f, a5 = 0.f, a6 = 0.f, a7 = 0.f;
    for (int j = beg; j < end; j += 8) {
        vint4 na = __builtin_nontemporal_load((const vint4*)(nbr + j));
        vint4 nb = __builtin_nontemporal_load((const vint4*)(nbr + j + 4));
        #pragma unroll
        for (int k = 0; k < 8; ++k) {
            int id = (j + k < lim) ? ((k < 4) ? na[k] : nb[k - 4]) : N_NODES;
            float w = dinv[id];                  // dinv[N_NODES] == 0 (misc block)
            uint2 raw = src[(size_t)id * 8 + q];
            a0 += w * fp8d(raw.x);
            a1 += w * fp8d(raw.x >> 8);
            a2 += w * fp8d(raw.x >> 16);
            a3 += w * fp8d(raw.x >> 24);
            a4 += w * fp8d(raw.y);
            a5 += w * fp8d(raw.y >> 8);
            a6 += w * fp8d(raw.y >> 16);
            a7 += w * fp8d(raw.y >> 24);
        }
    }
    float s = d2[node] * FP8_INVSCALE;           // undo the x256 fp8 staging scale
    half8 r;
    r[0] = (_Float16)(s * a0); r[1] = (_Float16)(s * a1);
    r[2] = (_Float16)(s * a2); r[3] = (_Float16)(s * a3);
    r[4] = (_Float16)(s * a4); r[5] = (_Float16)(s * a5);
    r[6] = (_Float16)(s * a6); r[7] = (_Float16)(s * a7);
    ((half8*)z1)[(size_t)node * 8 + q] = r;   // plain store: z1 re-read (gathered) next pass
}

// ---------- prop layer 2 (node-ordered, flag-masked, fp16): z2 = d2 * sum z1 ----------
__global__ void prop_masked_k(const int* __restrict__ row_start, const int* __restrict__ nbr,
                              const int* __restrict__ deg, const float* __restrict__ d2,
                              const unsigned char* __restrict__ flag,
                              const _Float16* __restrict__ in, _Float16* __restrict__ out) {
    int t = blockIdx.x * blockDim.x + threadIdx.x;
    int node = t >> 3;
    int q = t & 7;
    if (node >= N_NODES) return;
    if (!flag[node]) return;   // z2 never read at unflagged nodes
    int d = deg[node];
    int beg = row_start[node];
    int lim = beg + d;
    int end = beg + ((d + 3) & ~3);
    const half8* src = (const half8*)in;
    float a0 = 0.f, a1 = 0.f, a2 = 0.f, a3 = 0.f, a4 = 0.f, a5 = 0.f, a6 = 0.f, a7 = 0.f;
    for (int j = beg; j < end; j += 8) {
        vint4 na = __builtin_nontemporal_load((const vint4*)(nbr + j));
        vint4 nb = __builtin_nontemporal_load((const vint4*)(nbr + j + 4));
        #pragma unroll
        for (int k = 0; k < 8; ++k) {
            int id = (j + k < lim) ? ((k < 4) ? na[k] : nb[k - 4]) : N_NODES;
            half8 h = src[(size_t)id * 8 + q];
            a0 += (float)h[0]; a1 += (float)h[1]; a2 += (float)h[2]; a3 += (float)h[3];
            a4 += (float)h[4]; a5 += (float)h[5]; a6 += (float)h[6]; a7 += (float)h[7];
        }
    }
    float s = d2[node];
    half8 r;
    r[0] = (_Float16)(s * a0); r[1] = (_Float16)(s * a1);
    r[2] = (_Float16)(s * a2); r[3] = (_Float16)(s * a3);
    r[4] = (_Float16)(s * a4); r[5] = (_Float16)(s * a5);
    r[6] = (_Float16)(s * a6); r[7] = (_Float16)(s * a7);
    ((half8*)out)[(size_t)node * 8 + q] = r;  // plain store: z2 re-read by score
}

// ---------- fused epilogue: layer-3 pull at queried nodes + layers 0-2 + dot ----------
// 16 lanes per (u,i) pair: 8 lanes user side, 8 lanes item side, 8 dims/lane
__global__ void fused_score_k(const int* __restrict__ row_start, const int* __restrict__ nbr,
                              const int* __restrict__ deg,
                              const float* __restrict__ dinv, const float* __restrict__ rcp,
                              const float* __restrict__ ue, const float* __restrict__ ie,
                              const _Float16* __restrict__ z1, const _Float16* __restrict__ z2,
                              const int* __restrict__ uid, const int* __restrict__ iid,
                              const float* __restrict__ w4, float* __restrict__ out) {
    int t = blockIdx.x * blockDim.x + threadIdx.x;
    int slot = t >> 4;
    if (slot >= BATCH) return;
    int within = t & 15;
    int side = within >> 3;
    int q = within & 7;

    int node;
    const float4* erow;
    if (side == 0) {
        int u = uid[slot];
        node = u;
        erow = (const float4*)ue + (size_t)u * 16;
    } else {
        int ii_ = iid[slot];
        node = NUM_USERS + ii_;
        erow = (const float4*)ie + (size_t)ii_ * 16;
    }

    float w0 = w4[0], w1 = w4[1], w2 = w4[2], w3 = w4[3];
    int d = deg[node];
    int beg = row_start[node];
    int lim = beg + d;
    int end = beg + ((d + 3) & ~3);
    const half8* z2v = (const half8*)z2;

    float a0 = 0.f, a1 = 0.f, a2 = 0.f, a3 = 0.f, a4 = 0.f, a5 = 0.f, a6 = 0.f, a7 = 0.f;
    for (int j = beg; j < end; j += 8) {
        vint4 na = __builtin_nontemporal_load((const vint4*)(nbr + j));
        vint4 nb = __builtin_nontemporal_load((const vint4*)(nbr + j + 4));
        #pragma unroll
        for (int k = 0; k < 8; ++k) {
            int id = (j + k < lim) ? ((k < 4) ? na[k] : nb[k - 4]) : N_NODES;
            half8 h = z2v[(size_t)id * 8 + q];
            a0 += (float)h[0]; a1 += (float)h[1]; a2 += (float)h[2]; a3 += (float)h[3];
            a4 += (float)h[4]; a5 += (float)h[5]; a6 += (float)h[6]; a7 += (float)h[7];
        }
    }

    float r  = rcp[node];
    float di = dinv[node];
    float e[8];
    *reinterpret_cast<float4*>(&e[0]) = erow[q * 2];
    *reinterpret_cast<float4*>(&e[4]) = erow[q * 2 + 1];
    half8 h1 = ((const half8*)z1)[(size_t)node * 8 + q];
    half8 h2 = z2v[(size_t)node * 8 + q];
    float acc[8] = {a0, a1, a2, a3, a4, a5, a6, a7};

    float f[8];
    #pragma unroll
    for (int dd = 0; dd < 8; ++dd)
        f[dd] = w0 * e[dd] + r * (w1 * (float)h1[dd] + w2 * (float)h2[dd]) + w3 * di * acc[dd];

    float pr = 0.f;
    #pragma unroll
    for (int dd = 0; dd < 8; ++dd) {
        float o = __shfl_xor(f[dd], 8);   // partner side, same dims
        pr += f[dd] * o;
    }
    pr += __shfl_xor(pr, 1);
    pr += __shfl_xor(pr, 2);
    pr += __shfl_xor(pr, 4);

    if (within == 0) out[slot] = pr;
}

// ---------- launch ----------

extern "C" void kernel_launch(void* const* d_in, const int* in_sizes, int n_in,
                              void* d_out, int out_size, void* d_ws, size_t ws_size,
                              hipStream_t stream) {
    const float* user_emb = (const float*)d_in[0];
    const float* item_emb = (const float*)d_in[1];
    const float* layer_w  = (const float*)d_in[2];
    const int*   inter_u  = (const int*)d_in[3];
    const int*   inter_i  = (const int*)d_in[4];
    const int*   user_ids = (const int*)d_in[5];
    const int*   item_ids = (const int*)d_in[6];
    float* out = (float*)d_out;

    char* base = (char*)d_ws;
    size_t off = 0;
    auto alloc = [&](size_t bytes) -> char* {
        char* p = base + off;
        off = (off + bytes + 255) & ~(size_t)255;
        return p;
    };
    float*    w4        = (float*)    alloc(4 * sizeof(float));
    int*      deg       = (int*)      alloc((size_t)N_NODES * sizeof(int));
    float*    dinv      = (float*)    alloc(((size_t)N_NODES + 1) * sizeof(float));  // +1: padding slot
    float*    d2        = (float*)    alloc((size_t)N_NODES * sizeof(float));
    float*    rcp       = (float*)    alloc((size_t)N_NODES * sizeof(float));
    int*      row_start = (int*)      alloc((size_t)N_NODES * sizeof(int));
    // zeroed region: flag + qflag + cursor (adjacent; single memset)
    unsigned char* flag   = (unsigned char*)alloc((size_t)N_NODES + 256);
    unsigned char* qflag  = (unsigned char*)alloc((size_t)N_NODES + 512);
    int*           cursor = (int*)          alloc((size_t)NBKT * 16 * sizeof(int));
    unsigned* pairs     = (unsigned*) alloc((size_t)NBKT * CAP * sizeof(unsigned));
    int*      csr_nbr   = (int*)      alloc((size_t)NBKT * RSLOTS * sizeof(int));
    unsigned char* semb = (unsigned char*)alloc(((size_t)N_NODES + 1) * EMB);        // fp8 e4m3
    _Float16* zA        = (_Float16*) alloc(((size_t)N_NODES + 1) * EMB * sizeof(_Float16));
    _Float16* zB        = (_Float16*) alloc(((size_t)N_NODES + 1) * EMB * sizeof(_Float16));

    // 1. zero flag + qflag + bucket cursors (adjacent allocations, single memset)
    size_t span = (size_t)((char*)cursor - (char*)flag) + (size_t)NBKT * 16 * sizeof(int);
    hipMemsetAsync(flag, 0, span, stream);

    // 2. qmark + misc + bucket scatter + fp8 emb cast (dependency-free conv rides here)
    bucket_scatter_k<<<QMARK_BLOCKS + 1 + AB_BLOCKS + CONV_BLOCKS, 256, 0, stream>>>(
        inter_u, inter_i, user_ids, item_ids, cursor, pairs, qflag, flag,
        layer_w, w4, dinv, user_emb, item_emb, semb, zB, zA);

    // 3. bucket-local CSR: degrees + factors + row_start + scatter (1024-thread blocks)
    bucket_all_k<<<NBKT, 1024, 0, stream>>>(
        cursor, pairs, qflag, flag, deg, dinv, d2, rcp, row_start, csr_nbr);

    // 4. layer 1 full (fp8 sum-gather, dinv applied at gather): zB = z1
    prop_first_k<<<PROP_BLOCKS, 256, 0, stream>>>(
        row_start, csr_nbr, deg, d2, dinv, semb, zB);

    // 5. layer 2 flag-masked, node-ordered, fp16: zA = z2
    prop_masked_k<<<PROP_BLOCKS, 256, 0, stream>>>(
        row_start, csr_nbr, deg, d2, flag, zB, zA);

    // 6. fused: layer-3 pull at queried nodes + layer 0-2 terms + dot product
    fused_score_k<<<(BATCH * 16 + 255) / 256, 256, 0, stream>>>(
        row_start, csr_nbr, deg, dinv, rcp, user_emb, item_emb,
        zB /*z1*/, zA /*z2*/, user_ids, item_ids, w4, out);
}